// Round 10
// baseline (422.382 us; speedup 1.0000x reference)
//
#include <hip/hip_runtime.h>
#include <cstdint>
#include <cstddef>

typedef __attribute__((ext_vector_type(4))) float f32x4;
typedef __attribute__((ext_vector_type(16))) float f32x16;
typedef __attribute__((ext_vector_type(8))) short bf16x8;
typedef __attribute__((ext_vector_type(2))) unsigned int u32x2;

#define S_LEN   2048
#define HID     4096
#define NH      32
#define NKV     8
#define HD      128
#define QKV_N   6144   /* 4096 Q + 1024 K + 1024 V */

typedef const __attribute__((address_space(1))) unsigned int* gptr_t;
typedef __attribute__((address_space(3))) unsigned int* lptr_t;

__device__ __forceinline__ void gload_lds16(const void* g, void* l) {
  __builtin_amdgcn_global_load_lds((gptr_t)g, (lptr_t)l, 16, 0, 0);
}

__device__ __forceinline__ ushort f2bf(float f) {
  union { float f; uint32_t u; } v; v.f = f;
  uint32_t r = v.u + 0x7FFFu + ((v.u >> 16) & 1u);
  return (ushort)(r >> 16);
}
__device__ __forceinline__ float bf2f(ushort u) {
  union { uint32_t u; float f; } v; v.u = ((uint32_t)u) << 16;
  return v.f;
}

// ---------------- cast f32 -> bf16 (vectorized) ----------------
__global__ void cast_f32_bf16(const float* __restrict__ in, ushort* __restrict__ out, int n) {
  int i = (blockIdx.x * 256 + threadIdx.x) * 4;
  if (i >= n) return;
  float4 v = *reinterpret_cast<const float4*>(in + i);
  ushort4 o;
  o.x = f2bf(v.x); o.y = f2bf(v.y); o.z = f2bf(v.z); o.w = f2bf(v.w);
  *reinterpret_cast<ushort4*>(out + i) = o;
}

// ---------------- transpose + cast: in f32 [R][C] -> out bf16 [C][R] ----------------
__global__ void transpose_cast(const float* __restrict__ in, ushort* __restrict__ out, int R, int C) {
  __shared__ float t[32][33];
  int tx = threadIdx.x & 31, ty = threadIdx.x >> 5;  // 32 x 8
  int r0 = blockIdx.y * 32, c0 = blockIdx.x * 32;
#pragma unroll
  for (int i = 0; i < 32; i += 8)
    t[ty + i][tx] = in[(size_t)(r0 + ty + i) * C + c0 + tx];
  __syncthreads();
#pragma unroll
  for (int i = 0; i < 32; i += 8)
    out[(size_t)(c0 + ty + i) * R + r0 + tx] = f2bf(t[tx][ty + i]);
}

// ---------------- pipelined GEMM: C[M][N] = A[M][K] * B^T (B stored [N][K]) ----------------
// BM x 256 tile, BK=32, 512 threads (8 waves 2Mx4N; per-wave BM/2 x 64 out).
// 3-slot LDS ring, 2-K-tile lookahead, 2 phases/K-tile (counted vmcnt, T4):
//  P0: stage A(t+2); vmcnt(2A+B in flight) -> A(t),B(t) retired (per-wave FIFO A,B,A,B);
//      barrier; ds_read a-frags + b0,b1; MFMA n-lo; barrier.
//  P1: stage B(t+2); ds_read b2,b3; MFMA n-hi; barrier (guards ring-slot reuse: slot
//      (t+3)%3 == t%3 is overwritten only after this barrier).
// BM=128: LDS 72KB -> 2 blocks/CU (keeps m114 inter-block overlap; R7's 1-block/CU regressed).
// T2 swizzle: chunk' = chunk ^ ((row>>1)&3), same involution on source and read.
// R9 bug fixed: ALOADS = BM/128 (A tile is 4*BM chunks / 512 threads); BM/64 over-ran the slot.
template <int BM, bool BF16_OUT>
__global__ __launch_bounds__(512, 2) void gemm_pipe(
    const ushort* __restrict__ A, const ushort* __restrict__ B,
    void* __restrict__ Cp, int N, int K) {
  constexpr int MR = BM / 32;              // m-frags per wave
  constexpr int ALOADS = BM / 128;         // per-thread loads per A unit (1 for BM=128)
  __shared__ ushort a_lds[3][BM * 32];
  __shared__ ushort b_lds[3][256 * 32];
  const int tid = threadIdx.x;
  const int wid = tid >> 6, lane = tid & 63;
  const int l16 = lane & 15, lk = lane >> 4;
  const int wr = wid >> 2, wc = wid & 3;
  const size_t a_row0 = (size_t)blockIdx.y * BM;
  const size_t b_row0 = (size_t)blockIdx.x * 256;

  f32x4 acc[MR][4] = {};
  const int NT = K >> 5;
  const int cswz = lk ^ ((l16 >> 1) & 3);  // read-side chunk swizzle

  auto stageA = [&](int slot, int t) {
    const size_t kb = (size_t)t << 5;
#pragma unroll
    for (int i = 0; i < ALOADS; ++i) {
      int c = i * 512 + tid;               // A: 4*BM 16B-chunks (4 per 64B row)
      int row = c >> 2, p = c & 3;
      int src = p ^ ((row >> 1) & 3);      // involution: pre-swizzled source
      gload_lds16(A + (a_row0 + row) * K + kb + src * 8, &a_lds[slot][c * 8]);
    }
  };
  auto stageB = [&](int slot, int t) {
    const size_t kb = (size_t)t << 5;
#pragma unroll
    for (int i = 0; i < 2; ++i) {
      int c = i * 512 + tid;               // B: 1024 chunks
      int row = c >> 2, p = c & 3;
      int src = p ^ ((row >> 1) & 3);
      gload_lds16(B + (b_row0 + row) * K + kb + src * 8, &b_lds[slot][c * 8]);
    }
  };

  // prologue: FIFO order A0,B0,A1,B1 (matches loop's A,B,A,B interleave)
  stageA(0, 0); stageB(0, 0);
  stageA(1, 1); stageB(1, 1);

  for (int t = 0; t < NT; ++t) {
    const int cur = t % 3;

    // ---- P0 ----
    if (t + 2 < NT) stageA((t + 2) % 3, t + 2);
    // in-flight after this stage (steady): A(t+1)+B(t+1)+A(t+2) = 2*ALOADS+2 units
    if (t < NT - 2) {
      if constexpr (BM == 256) asm volatile("s_waitcnt vmcnt(6)" ::: "memory");
      else                     asm volatile("s_waitcnt vmcnt(4)" ::: "memory");
    } else if (t == NT - 2) {
      if constexpr (BM == 256) asm volatile("s_waitcnt vmcnt(4)" ::: "memory");
      else                     asm volatile("s_waitcnt vmcnt(3)" ::: "memory");
    } else {
      asm volatile("s_waitcnt vmcnt(0)" ::: "memory");
    }
    __builtin_amdgcn_s_barrier();          // all waves' A(t),B(t) shares landed

    bf16x8 af[MR], b01[2], b23[2];
#pragma unroll
    for (int m = 0; m < MR; ++m) {
      int row = wr * (BM / 2) + m * 16 + l16;
      af[m] = *reinterpret_cast<const bf16x8*>(&a_lds[cur][row * 32 + cswz * 8]);
    }
#pragma unroll
    for (int n = 0; n < 2; ++n) {
      int row = wc * 64 + n * 16 + l16;
      b01[n] = *reinterpret_cast<const bf16x8*>(&b_lds[cur][row * 32 + cswz * 8]);
    }
    asm volatile("s_waitcnt lgkmcnt(0)" ::: "memory");
    __builtin_amdgcn_s_setprio(1);
#pragma unroll
    for (int m = 0; m < MR; ++m)
#pragma unroll
      for (int n = 0; n < 2; ++n)
        acc[m][n] = __builtin_amdgcn_mfma_f32_16x16x32_bf16(af[m], b01[n], acc[m][n], 0, 0, 0);
    __builtin_amdgcn_s_setprio(0);
    __builtin_amdgcn_s_barrier();

    // ---- P1 ----
    if (t + 2 < NT) stageB((t + 2) % 3, t + 2);
#pragma unroll
    for (int n = 0; n < 2; ++n) {
      int row = wc * 64 + 32 + n * 16 + l16;
      b23[n] = *reinterpret_cast<const bf16x8*>(&b_lds[cur][row * 32 + cswz * 8]);
    }
    asm volatile("s_waitcnt lgkmcnt(0)" ::: "memory");
    __builtin_amdgcn_s_setprio(1);
#pragma unroll
    for (int m = 0; m < MR; ++m)
#pragma unroll
      for (int n = 0; n < 2; ++n)
        acc[m][2 + n] = __builtin_amdgcn_mfma_f32_16x16x32_bf16(af[m], b23[n], acc[m][2 + n], 0, 0, 0);
    __builtin_amdgcn_s_setprio(0);
    __builtin_amdgcn_s_barrier();          // guards slot reuse
  }

  // epilogue (verified C/D mapping: col=lane&15, row=(lane>>4)*4+reg)
#pragma unroll
  for (int m = 0; m < MR; ++m) {
    size_t row_b = a_row0 + wr * (BM / 2) + m * 16 + lk * 4;
#pragma unroll
    for (int n = 0; n < 4; ++n) {
      int col = (int)b_row0 + wc * 64 + n * 16 + l16;
#pragma unroll
      for (int r = 0; r < 4; ++r) {
        if constexpr (BF16_OUT)
          ((ushort*)Cp)[(row_b + r) * N + col] = f2bf(acc[m][n][r]);
        else
          ((float*)Cp)[(row_b + r) * N + col] = acc[m][n][r];
      }
    }
  }
}

// ---------------- RoPE in-place on Q (cols 0..4095) and K (cols 4096..5119) of QKV ----------------
__global__ void rope_kernel(ushort* __restrict__ QKV) {
  int idx = blockIdx.x * 256 + threadIdx.x;  // 2048 * 40 * 8 threads
  int dg = idx & 7;
  int t = idx >> 3;
  int s = t / 40;
  int hh = t - s * 40;
  if (s >= S_LEN) return;
  int col = (hh < NH) ? hh * HD : HID + (hh - NH) * HD;
  ushort* base = QKV + (size_t)s * QKV_N + col + dg * 8;

  union U { uint4 v; ushort u[8]; };
  U L, H, OL, OH;
  L.v = *reinterpret_cast<const uint4*>(base);
  H.v = *reinterpret_cast<const uint4*>(base + 64);
  const float C0 = 13.287712379549449f / 64.0f;  // log2(10000)/64
#pragma unroll
  for (int j = 0; j < 8; ++j) {
    int d = dg * 8 + j;
    float invf = exp2f(-(float)d * C0);
    float ang = (float)s * invf;
    float sn, cs;
    sincosf(ang, &sn, &cs);
    float xl = bf2f(L.u[j]), xh = bf2f(H.u[j]);
    OL.u[j] = f2bf(xl * cs - xh * sn);
    OH.u[j] = f2bf(xh * cs + xl * sn);
  }
  *reinterpret_cast<uint4*>(base) = OL.v;
  *reinterpret_cast<uint4*>(base + 64) = OH.v;
}

// ---------------- V slice of QKV -> Vt[8][128][2048] ----------------
__global__ void transpose_v(const ushort* __restrict__ QKV, ushort* __restrict__ Vt) {
  __shared__ ushort t[64][65];
  int s0 = blockIdx.x * 64;
  int d0 = blockIdx.y * 64;
  int hkv = blockIdx.z;
  int tx = threadIdx.x & 63, ty = threadIdx.x >> 6;  // 64 x 4
#pragma unroll
  for (int i = 0; i < 64; i += 4)
    t[i + ty][tx] = QKV[(size_t)(s0 + i + ty) * QKV_N + HID + NKV * HD + hkv * HD + d0 + tx];
  __syncthreads();
#pragma unroll
  for (int i = 0; i < 64; i += 4)
    Vt[((size_t)hkv * HD + d0 + i + ty) * S_LEN + s0 + tx] = t[tx][i + ty];
}

// ---------------- flash attention: swapped-QK^T 32x32 MFMA, in-register softmax ----------------
// Grid = 256 blocks (one full-chip round). h=(lin&7)*4+((lin>>3)&3), p=lin>>5;
// block does q-panels {p, 15-p} -> uniform 34 KV-tiles; XCD-local KV (1MB per hkv, L2-fits).
__global__ __launch_bounds__(256, 2) void attn_kernel(
    const ushort* __restrict__ QKV, const ushort* __restrict__ Vt, ushort* __restrict__ AO) {
  constexpr float SCALE = 0.08838834764831845f;  // 1/sqrt(128)
  __shared__ ushort k_lds[2][64 * 128];   // [krow][128 d], 16B chunks XOR-swizzled by (row&7)
  __shared__ ushort v_lds[2][128 * 64];   // [d][64 s], 16B chunks XOR-swizzled by (row&7)

  const int lin = blockIdx.x;
  const int h = ((lin & 7) << 2) + ((lin >> 3) & 3);
  const int p = lin >> 5;                 // 0..7
  const int hkv = h >> 2;
  const int tid = threadIdx.x, wid = tid >> 6, lane = tid & 63;
  const int l32 = lane & 31;
  const int hi = lane >> 5;

  auto stageKV = [&](int buf, int kt) {
#pragma unroll
    for (int i = 0; i < 4; ++i) {
      int c = i * 256 + wid * 64 + lane;
      int row = c >> 4, ch = c & 15;
      int sch = ch ^ (row & 7);
      gload_lds16(QKV + (size_t)(kt * 64 + row) * QKV_N + HID + hkv * HD + sch * 8,
                  &k_lds[buf][c * 8]);
    }
#pragma unroll
    for (int i = 0; i < 4; ++i) {
      int c = i * 256 + wid * 64 + lane;
      int row = c >> 3, ch = c & 7;
      int sch = ch ^ (row & 7);
      gload_lds16(Vt + ((size_t)hkv * HD + row) * S_LEN + (size_t)kt * 64 + sch * 8,
                  &v_lds[buf][c * 8]);
    }
  };

  for (int pi = 0; pi < 2; ++pi) {
    const int qb = pi ? (15 - p) : p;
    const int q0 = qb * 128;
    const int qg = q0 + wid * 32 + l32;   // this lane's q row

    bf16x8 qf[8];
    {
      const ushort* qrow = QKV + (size_t)qg * QKV_N + h * HD + hi * 8;
#pragma unroll
      for (int ds = 0; ds < 8; ++ds)
        qf[ds] = *reinterpret_cast<const bf16x8*>(qrow + ds * 16);
    }

    float m_run = -1e30f, l_run = 0.f;
    f32x16 oacc[4] = {};   // oacc[f][r] = O[q=l32][d = f*32 + crow(r,hi)]

    stageKV(0, 0);
    __syncthreads();

    const int nt = 2 * qb + 2;
    for (int kt = 0; kt < nt; ++kt) {
      const int cur = kt & 1;
      if (kt + 1 < nt) stageKV(cur ^ 1, kt + 1);

      if (kt * 64 <= q0 + wid * 32 + 31) {
        float pv[32];
        __builtin_amdgcn_s_setprio(1);
#pragma unroll
        for (int kf = 0; kf < 2; ++kf) {
          f32x16 s = {};
          int rk = kf * 32 + l32;
#pragma unroll
          for (int ds = 0; ds < 8; ++ds) {
            int c16 = (ds * 2 + hi) ^ (rk & 7);
            bf16x8 kfr = *reinterpret_cast<const bf16x8*>(&k_lds[cur][rk * 128 + c16 * 8]);
            s = __builtin_amdgcn_mfma_f32_32x32x16_bf16(kfr, qf[ds], s, 0, 0, 0);
          }
#pragma unroll
          for (int r = 0; r < 16; ++r) pv[kf * 16 + r] = s[r] * SCALE;
        }
        __builtin_amdgcn_s_setprio(0);

        if (kt * 64 + 63 > q0 + wid * 32) {  // diagonal tile: causal mask
#pragma unroll
          for (int kf = 0; kf < 2; ++kf)
#pragma unroll
            for (int r = 0; r < 16; ++r) {
              int kl = kf * 32 + (r & 3) + 8 * (r >> 2) + 4 * hi;
              if (kt * 64 + kl > qg) pv[kf * 16 + r] = -1e30f;
            }
        }

        float mt = pv[0];
#pragma unroll
        for (int i = 1; i < 32; ++i) mt = fmaxf(mt, pv[i]);
        mt = fmaxf(mt, __shfl_xor(mt, 32, 64));
        float mn = fmaxf(m_run, mt);
        float alpha = __expf(m_run - mn);
        float ls = 0.f;
#pragma unroll
        for (int i = 0; i < 32; ++i) { pv[i] = __expf(pv[i] - mn); ls += pv[i]; }
        ls += __shfl_xor(ls, 32, 64);
        l_run = l_run * alpha + ls;
        m_run = mn;
#pragma unroll
        for (int f = 0; f < 4; ++f)
#pragma unroll
          for (int r = 0; r < 16; ++r) oacc[f][r] *= alpha;

        // pack P -> PV B-operand (T12: cvt_pk + permlane32_swap)
        union PW { uint32_t w[4]; bf16x8 v; } pa[4];
#pragma unroll
        for (int ks = 0; ks < 4; ++ks) {
          uint32_t x0, x1, y0, y1;
          asm("v_cvt_pk_bf16_f32 %0, %1, %2" : "=v"(x0) : "v"(pv[8 * ks + 0]), "v"(pv[8 * ks + 1]));
          asm("v_cvt_pk_bf16_f32 %0, %1, %2" : "=v"(x1) : "v"(pv[8 * ks + 2]), "v"(pv[8 * ks + 3]));
          asm("v_cvt_pk_bf16_f32 %0, %1, %2" : "=v"(y0) : "v"(pv[8 * ks + 4]), "v"(pv[8 * ks + 5]));
          asm("v_cvt_pk_bf16_f32 %0, %1, %2" : "=v"(y1) : "v"(pv[8 * ks + 6]), "v"(pv[8 * ks + 7]));
          u32x2 r0 = __builtin_amdgcn_permlane32_swap(x0, y0, false, false);
          u32x2 r1 = __builtin_amdgcn_permlane32_swap(x1, y1, false, false);
          pa[ks].w[0] = r0.x; pa[ks].w[1] = r1.x; pa[ks].w[2] = r0.y; pa[ks].w[3] = r1.y;
        }

        __builtin_amdgcn_s_setprio(1);
#pragma unroll
        for (int ks = 0; ks < 4; ++ks) {
#pragma unroll
          for (int f = 0; f < 4; ++f) {
            int dv = f * 32 + l32;
            int c8 = (2 * ks + hi) ^ (dv & 7);
            bf16x8 vfr = *reinterpret_cast<const bf16x8*>(&v_lds[cur][dv * 64 + c8 * 8]);
            oacc[f] = __builtin_amdgcn_mfma_f32_32x32x16_bf16(vfr, pa[ks].v, oacc[f], 0, 0, 0);
          }
        }
        __builtin_amdgcn_s_setprio(0);
      }

      __syncthreads();
    }

    float inv_l = 1.0f / l_run;
    ushort* aorow = AO + (size_t)qg * HID + h * HD;
#pragma unroll
    for (int f = 0; f < 4; ++f)
#pragma unroll
      for (int g = 0; g < 4; ++g) {
        ushort4 o;
        o.x = f2bf(oacc[f][g * 4 + 0] * inv_l);
        o.y = f2bf(oacc[f][g * 4 + 1] * inv_l);
        o.z = f2bf(oacc[f][g * 4 + 2] * inv_l);
        o.w = f2bf(oacc[f][g * 4 + 3] * inv_l);
        *reinterpret_cast<ushort4*>(aorow + f * 32 + g * 8 + 4 * hi) = o;
      }
  }
}

// ---------------- launcher ----------------
extern "C" void kernel_launch(void* const* d_in, const int* in_sizes, int n_in,
                              void* d_out, int out_size, void* d_ws, size_t ws_size,
                              hipStream_t stream) {
  (void)in_sizes; (void)n_in; (void)out_size;
  const float* hs = (const float*)d_in[0];
  const float* Wq = (const float*)d_in[1];
  const float* Wk = (const float*)d_in[2];
  const float* Wv = (const float*)d_in[3];
  const float* Wo = (const float*)d_in[4];
  float* out = (float*)d_out;

  // workspace layout (bytes)
  char* ws = (char*)d_ws;
  const size_t OFF_HSB   = 0;                         // 2048*4096 bf16 = 16 MB
  const size_t OFF_WQKVT = OFF_HSB + 16777216;        // 6144*4096 bf16 = 48 MB
  const size_t OFF_WOT   = OFF_WQKVT + 50331648;      // 4096*4096 bf16 = 32 MB
  const size_t OFF_QKV   = OFF_WOT + 33554432;        // 2048*6144 bf16 = 24 MB
  const size_t OFF_VT    = OFF_QKV + 25165824;        // 8*128*2048 bf16 = 4 MB
  const size_t OFF_AO    = OFF_VT + 4194304;          // 2048*4096 bf16 = 16 MB
  if (ws_size < OFF_AO + 16777216) return;            // ~140 MB needed

  ushort* hsb   = (ushort*)(ws + OFF_HSB);
  ushort* WqkvT = (ushort*)(ws + OFF_WQKVT);
  ushort* WoT   = (ushort*)(ws + OFF_WOT);
  ushort* QKV   = (ushort*)(ws + OFF_QKV);
  ushort* Vt    = (ushort*)(ws + OFF_VT);
  ushort* AO    = (ushort*)(ws + OFF_AO);

  cast_f32_bf16<<<8192, 256, 0, stream>>>(hs, hsb, S_LEN * HID);
  transpose_cast<<<dim3(4096 / 32, 4096 / 32), 256, 0, stream>>>(Wq, WqkvT, HID, 4096);
  transpose_cast<<<dim3(1024 / 32, 4096 / 32), 256, 0, stream>>>(Wk, WqkvT + (size_t)4096 * HID, HID, 1024);
  transpose_cast<<<dim3(1024 / 32, 4096 / 32), 256, 0, stream>>>(Wv, WqkvT + (size_t)5120 * HID, HID, 1024);
  transpose_cast<<<dim3(4096 / 32, 4096 / 32), 256, 0, stream>>>(Wo, WoT, 4096, HID);

  gemm_pipe<128, true><<<dim3(QKV_N / 256, S_LEN / 128), 512, 0, stream>>>(hsb, WqkvT, QKV, QKV_N, HID);
  rope_kernel<<<(S_LEN * 40 * 8) / 256, 256, 0, stream>>>(QKV);
  transpose_v<<<dim3(S_LEN / 64, HD / 64, NKV), 256, 0, stream>>>(QKV, Vt);
  attn_kernel<<<256, 256, 0, stream>>>(QKV, Vt, AO);
  gemm_pipe<128, false><<<dim3(HID / 256, S_LEN / 128), 512, 0, stream>>>(AO, WoT, out, HID, HID);
}

// Round 11
// 367.368 us; speedup vs baseline: 1.1498x; 1.1498x over previous
//
#include <hip/hip_runtime.h>
#include <cstdint>
#include <cstddef>

typedef __attribute__((ext_vector_type(4))) float f32x4;
typedef __attribute__((ext_vector_type(16))) float f32x16;
typedef __attribute__((ext_vector_type(8))) short bf16x8;
typedef __attribute__((ext_vector_type(2))) unsigned int u32x2;

#define S_LEN   2048
#define HID     4096
#define NH      32
#define NKV     8
#define HD      128
#define QKV_N   6144   /* 4096 Q + 1024 K + 1024 V */

typedef const __attribute__((address_space(1))) unsigned int* gptr_t;
typedef __attribute__((address_space(3))) unsigned int* lptr_t;

__device__ __forceinline__ void gload_lds16(const void* g, void* l) {
  __builtin_amdgcn_global_load_lds((gptr_t)g, (lptr_t)l, 16, 0, 0);
}

__device__ __forceinline__ ushort f2bf(float f) {
  union { float f; uint32_t u; } v; v.f = f;
  uint32_t r = v.u + 0x7FFFu + ((v.u >> 16) & 1u);
  return (ushort)(r >> 16);
}
__device__ __forceinline__ float bf2f(ushort u) {
  union { uint32_t u; float f; } v; v.u = ((uint32_t)u) << 16;
  return v.f;
}

// ---------------- cast f32 -> bf16 (vectorized) ----------------
__global__ void cast_f32_bf16(const float* __restrict__ in, ushort* __restrict__ out, int n) {
  int i = (blockIdx.x * 256 + threadIdx.x) * 4;
  if (i >= n) return;
  float4 v = *reinterpret_cast<const float4*>(in + i);
  ushort4 o;
  o.x = f2bf(v.x); o.y = f2bf(v.y); o.z = f2bf(v.z); o.w = f2bf(v.w);
  *reinterpret_cast<ushort4*>(out + i) = o;
}

// ---------------- transpose + cast: in f32 [R][C] -> out bf16 [C][R] ----------------
__global__ void transpose_cast(const float* __restrict__ in, ushort* __restrict__ out, int R, int C) {
  __shared__ float t[32][33];
  int tx = threadIdx.x & 31, ty = threadIdx.x >> 5;  // 32 x 8
  int r0 = blockIdx.y * 32, c0 = blockIdx.x * 32;
#pragma unroll
  for (int i = 0; i < 32; i += 8)
    t[ty + i][tx] = in[(size_t)(r0 + ty + i) * C + c0 + tx];
  __syncthreads();
#pragma unroll
  for (int i = 0; i < 32; i += 8)
    out[(size_t)(c0 + ty + i) * R + r0 + tx] = f2bf(t[tx][ty + i]);
}

// ---------------- 8-phase GEMM (m201 template): C[M][N] = A[M][K]*B^T, 256x256 tile ----
// BK=64, 512 threads (8 waves 2Mx4N; per-wave 128x64). LDS = 2buf x 2half x 128x64 x {A,B}
// = 128 KiB. 4 phases per K-tile, each: {ds_read subtile; stage 1 half-tile; barrier;
// lgkmcnt(0); setprio1; 16 MFMA (one 64x32 C-quadrant x K=64); setprio0; barrier}.
// Stage stream: ph1->B0(t+1), ph2->B1(t+1), ph3->A0(t+2), ph4->A1(t+2); each target's
// last LDS reader finished >=1 closing-barrier before the stage issues.
// vmcnt(4) once per K-tile at ph4: retires A(t+1),B(t+1), leaves A(t+2) in flight (T4 —
// never drains mid-loop). Chunk-XOR swizzle ch^(row&7) on stage source + reads (T2).
template <bool BF16_OUT>
__global__ __launch_bounds__(512, 2) void gemm_8ph(
    const ushort* __restrict__ A, const ushort* __restrict__ B,
    void* __restrict__ Cp, int N, int K) {
  __shared__ ushort a_lds[2][2][128 * 64];   // [buf][half][row*64 + chunk*8 + e]
  __shared__ ushort b_lds[2][2][128 * 64];
  const int tid = threadIdx.x;
  const int wid = tid >> 6, lane = tid & 63;
  const int l16 = lane & 15, lk = lane >> 4;
  const int wr = wid >> 2, wc = wid & 3;
  const int bh = wc >> 1;                    // B-half this wave reads
  const int brb = (wc & 1) * 64;             // B local-row base within the half
  const size_t a_row0 = (size_t)blockIdx.y * 256;
  const size_t b_row0 = (size_t)blockIdx.x * 256;
  const int NT = K >> 6;

  f32x4 acc[8][4] = {};

  auto stageA = [&](int buf, int h, int t) {   // 128x64 bf16 half-tile, 2 loads/thread
#pragma unroll
    for (int i = 0; i < 2; ++i) {
      int c = i * 512 + tid;
      int row = c >> 3, pos = c & 7, src = pos ^ (row & 7);
      gload_lds16(A + (a_row0 + h * 128 + row) * K + ((size_t)t << 6) + src * 8,
                  &a_lds[buf][h][c * 8]);
    }
  };
  auto stageB = [&](int buf, int h, int t) {
#pragma unroll
    for (int i = 0; i < 2; ++i) {
      int c = i * 512 + tid;
      int row = c >> 3, pos = c & 7, src = pos ^ (row & 7);
      gload_lds16(B + (b_row0 + h * 128 + row) * K + ((size_t)t << 6) + src * 8,
                  &b_lds[buf][h][c * 8]);
    }
  };

  // prologue (FIFO): A0(0) A1(0) B0(0) B1(0) A0(1) A1(1); tile0 landed, A(1) in flight
  stageA(0, 0, 0); stageA(0, 1, 0); stageB(0, 0, 0); stageB(0, 1, 0);
  if (NT > 1) {
    stageA(1, 0, 1); stageA(1, 1, 1);
    asm volatile("s_waitcnt vmcnt(4)" ::: "memory");
  } else {
    asm volatile("s_waitcnt vmcnt(0)" ::: "memory");
  }
  __builtin_amdgcn_s_barrier();

  for (int t = 0; t < NT; ++t) {
    const int d = t & 1;
    bf16x8 a[8][2], bl[2][2];

    // ---- ph1: read a_lo(8) + b_lo(4); stage B0(t+1); MFMA Q00 ----
#pragma unroll
    for (int m = 0; m < 4; ++m)
#pragma unroll
      for (int kk = 0; kk < 2; ++kk) {
        int r = m * 16 + l16;
        int ch = (kk * 4 + lk) ^ (r & 7);
        a[m][kk] = *reinterpret_cast<const bf16x8*>(&a_lds[d][wr][r * 64 + ch * 8]);
      }
#pragma unroll
    for (int n = 0; n < 2; ++n)
#pragma unroll
      for (int kk = 0; kk < 2; ++kk) {
        int r = brb + n * 16 + l16;
        int ch = (kk * 4 + lk) ^ (r & 7);
        bl[n][kk] = *reinterpret_cast<const bf16x8*>(&b_lds[d][bh][r * 64 + ch * 8]);
      }
    if (t + 1 < NT) stageB(d ^ 1, 0, t + 1);
    __builtin_amdgcn_s_barrier();
    asm volatile("s_waitcnt lgkmcnt(0)" ::: "memory");
    __builtin_amdgcn_s_setprio(1);
#pragma unroll
    for (int m = 0; m < 4; ++m)
#pragma unroll
      for (int n = 0; n < 2; ++n)
#pragma unroll
        for (int kk = 0; kk < 2; ++kk)
          acc[m][n] = __builtin_amdgcn_mfma_f32_16x16x32_bf16(a[m][kk], bl[n][kk], acc[m][n], 0, 0, 0);
    __builtin_amdgcn_s_setprio(0);
    __builtin_amdgcn_s_barrier();

    // ---- ph2: read a_hi(8); stage B1(t+1); MFMA Q10 (a_hi x b_lo) ----
#pragma unroll
    for (int m = 0; m < 4; ++m)
#pragma unroll
      for (int kk = 0; kk < 2; ++kk) {
        int r = 64 + m * 16 + l16;
        int ch = (kk * 4 + lk) ^ (r & 7);
        a[4 + m][kk] = *reinterpret_cast<const bf16x8*>(&a_lds[d][wr][r * 64 + ch * 8]);
      }
    if (t + 1 < NT) stageB(d ^ 1, 1, t + 1);
    __builtin_amdgcn_s_barrier();
    asm volatile("s_waitcnt lgkmcnt(0)" ::: "memory");
    __builtin_amdgcn_s_setprio(1);
#pragma unroll
    for (int m = 0; m < 4; ++m)
#pragma unroll
      for (int n = 0; n < 2; ++n)
#pragma unroll
        for (int kk = 0; kk < 2; ++kk)
          acc[4 + m][n] = __builtin_amdgcn_mfma_f32_16x16x32_bf16(a[4 + m][kk], bl[n][kk], acc[4 + m][n], 0, 0, 0);
    __builtin_amdgcn_s_setprio(0);
    __builtin_amdgcn_s_barrier();

    // ---- ph3: read b_hi(4) into bl (b_lo dead); stage A0(t+2); MFMA Q01 (a_lo x b_hi) ----
#pragma unroll
    for (int n = 0; n < 2; ++n)
#pragma unroll
      for (int kk = 0; kk < 2; ++kk) {
        int r = brb + 32 + n * 16 + l16;
        int ch = (kk * 4 + lk) ^ (r & 7);
        bl[n][kk] = *reinterpret_cast<const bf16x8*>(&b_lds[d][bh][r * 64 + ch * 8]);
      }
    if (t + 2 < NT) stageA(d, 0, t + 2);
    __builtin_amdgcn_s_barrier();
    asm volatile("s_waitcnt lgkmcnt(0)" ::: "memory");
    __builtin_amdgcn_s_setprio(1);
#pragma unroll
    for (int m = 0; m < 4; ++m)
#pragma unroll
      for (int n = 0; n < 2; ++n)
#pragma unroll
        for (int kk = 0; kk < 2; ++kk)
          acc[m][2 + n] = __builtin_amdgcn_mfma_f32_16x16x32_bf16(a[m][kk], bl[n][kk], acc[m][2 + n], 0, 0, 0);
    __builtin_amdgcn_s_setprio(0);
    __builtin_amdgcn_s_barrier();

    // ---- ph4: stage A1(t+2); MFMA Q11 (a_hi x b_hi); vmcnt; barrier ----
    if (t + 2 < NT) stageA(d, 1, t + 2);
    __builtin_amdgcn_s_barrier();
    __builtin_amdgcn_s_setprio(1);
#pragma unroll
    for (int m = 0; m < 4; ++m)
#pragma unroll
      for (int n = 0; n < 2; ++n)
#pragma unroll
        for (int kk = 0; kk < 2; ++kk)
          acc[4 + m][2 + n] = __builtin_amdgcn_mfma_f32_16x16x32_bf16(a[4 + m][kk], bl[n][kk], acc[4 + m][2 + n], 0, 0, 0);
    __builtin_amdgcn_s_setprio(0);
    // retire A(t+1),B(t+1); keep A(t+2)'s 4 loads in flight (counted, never drains mid-loop)
    if (t + 2 < NT) asm volatile("s_waitcnt vmcnt(4)" ::: "memory");
    else            asm volatile("s_waitcnt vmcnt(0)" ::: "memory");
    __builtin_amdgcn_s_barrier();
  }

  // epilogue (verified C/D map: col = lane&15, row = (lane>>4)*4 + reg)
#pragma unroll
  for (int m = 0; m < 8; ++m) {
    size_t row_b = a_row0 + wr * 128 + m * 16 + lk * 4;
#pragma unroll
    for (int n = 0; n < 4; ++n) {
      int col = (int)b_row0 + wc * 64 + n * 16 + l16;
#pragma unroll
      for (int r = 0; r < 4; ++r) {
        if constexpr (BF16_OUT)
          ((ushort*)Cp)[(row_b + r) * N + col] = f2bf(acc[m][n][r]);
        else
          ((float*)Cp)[(row_b + r) * N + col] = acc[m][n][r];
      }
    }
  }
}

// ---------------- RoPE in-place on Q (cols 0..4095) and K (cols 4096..5119) of QKV ----------------
__global__ void rope_kernel(ushort* __restrict__ QKV) {
  int idx = blockIdx.x * 256 + threadIdx.x;  // 2048 * 40 * 8 threads
  int dg = idx & 7;
  int t = idx >> 3;
  int s = t / 40;
  int hh = t - s * 40;
  if (s >= S_LEN) return;
  int col = (hh < NH) ? hh * HD : HID + (hh - NH) * HD;
  ushort* base = QKV + (size_t)s * QKV_N + col + dg * 8;

  union U { uint4 v; ushort u[8]; };
  U L, H, OL, OH;
  L.v = *reinterpret_cast<const uint4*>(base);
  H.v = *reinterpret_cast<const uint4*>(base + 64);
  const float C0 = 13.287712379549449f / 64.0f;  // log2(10000)/64
#pragma unroll
  for (int j = 0; j < 8; ++j) {
    int d = dg * 8 + j;
    float invf = exp2f(-(float)d * C0);
    float ang = (float)s * invf;
    float sn, cs;
    sincosf(ang, &sn, &cs);
    float xl = bf2f(L.u[j]), xh = bf2f(H.u[j]);
    OL.u[j] = f2bf(xl * cs - xh * sn);
    OH.u[j] = f2bf(xh * cs + xl * sn);
  }
  *reinterpret_cast<uint4*>(base) = OL.v;
  *reinterpret_cast<uint4*>(base + 64) = OH.v;
}

// ---------------- V slice of QKV -> Vt[8][128][2048] ----------------
__global__ void transpose_v(const ushort* __restrict__ QKV, ushort* __restrict__ Vt) {
  __shared__ ushort t[64][65];
  int s0 = blockIdx.x * 64;
  int d0 = blockIdx.y * 64;
  int hkv = blockIdx.z;
  int tx = threadIdx.x & 63, ty = threadIdx.x >> 6;  // 64 x 4
#pragma unroll
  for (int i = 0; i < 64; i += 4)
    t[i + ty][tx] = QKV[(size_t)(s0 + i + ty) * QKV_N + HID + NKV * HD + hkv * HD + d0 + tx];
  __syncthreads();
#pragma unroll
  for (int i = 0; i < 64; i += 4)
    Vt[((size_t)hkv * HD + d0 + i + ty) * S_LEN + s0 + tx] = t[tx][i + ty];
}

// ---------------- flash attention: swapped-QK^T 32x32 MFMA, in-register softmax ----------------
// Grid = 256 blocks (one full-chip round). h=(lin&7)*4+((lin>>3)&3), p=lin>>5;
// block does q-panels {p, 15-p} -> uniform 34 KV-tiles; XCD-local KV (1MB per hkv, L2-fits).
__global__ __launch_bounds__(256, 2) void attn_kernel(
    const ushort* __restrict__ QKV, const ushort* __restrict__ Vt, ushort* __restrict__ AO) {
  constexpr float SCALE = 0.08838834764831845f;  // 1/sqrt(128)
  __shared__ ushort k_lds[2][64 * 128];   // [krow][128 d], 16B chunks XOR-swizzled by (row&7)
  __shared__ ushort v_lds[2][128 * 64];   // [d][64 s], 16B chunks XOR-swizzled by (row&7)

  const int lin = blockIdx.x;
  const int h = ((lin & 7) << 2) + ((lin >> 3) & 3);
  const int p = lin >> 5;                 // 0..7
  const int hkv = h >> 2;
  const int tid = threadIdx.x, wid = tid >> 6, lane = tid & 63;
  const int l32 = lane & 31;
  const int hi = lane >> 5;

  auto stageKV = [&](int buf, int kt) {
#pragma unroll
    for (int i = 0; i < 4; ++i) {
      int c = i * 256 + wid * 64 + lane;
      int row = c >> 4, ch = c & 15;
      int sch = ch ^ (row & 7);
      gload_lds16(QKV + (size_t)(kt * 64 + row) * QKV_N + HID + hkv * HD + sch * 8,
                  &k_lds[buf][c * 8]);
    }
#pragma unroll
    for (int i = 0; i < 4; ++i) {
      int c = i * 256 + wid * 64 + lane;
      int row = c >> 3, ch = c & 7;
      int sch = ch ^ (row & 7);
      gload_lds16(Vt + ((size_t)hkv * HD + row) * S_LEN + (size_t)kt * 64 + sch * 8,
                  &v_lds[buf][c * 8]);
    }
  };

  for (int pi = 0; pi < 2; ++pi) {
    const int qb = pi ? (15 - p) : p;
    const int q0 = qb * 128;
    const int qg = q0 + wid * 32 + l32;   // this lane's q row

    bf16x8 qf[8];
    {
      const ushort* qrow = QKV + (size_t)qg * QKV_N + h * HD + hi * 8;
#pragma unroll
      for (int ds = 0; ds < 8; ++ds)
        qf[ds] = *reinterpret_cast<const bf16x8*>(qrow + ds * 16);
    }

    float m_run = -1e30f, l_run = 0.f;
    f32x16 oacc[4] = {};   // oacc[f][r] = O[q=l32][d = f*32 + crow(r,hi)]

    stageKV(0, 0);
    __syncthreads();

    const int nt = 2 * qb + 2;
    for (int kt = 0; kt < nt; ++kt) {
      const int cur = kt & 1;
      if (kt + 1 < nt) stageKV(cur ^ 1, kt + 1);

      if (kt * 64 <= q0 + wid * 32 + 31) {
        float pv[32];
        __builtin_amdgcn_s_setprio(1);
#pragma unroll
        for (int kf = 0; kf < 2; ++kf) {
          f32x16 s = {};
          int rk = kf * 32 + l32;
#pragma unroll
          for (int ds = 0; ds < 8; ++ds) {
            int c16 = (ds * 2 + hi) ^ (rk & 7);
            bf16x8 kfr = *reinterpret_cast<const bf16x8*>(&k_lds[cur][rk * 128 + c16 * 8]);
            s = __builtin_amdgcn_mfma_f32_32x32x16_bf16(kfr, qf[ds], s, 0, 0, 0);
          }
#pragma unroll
          for (int r = 0; r < 16; ++r) pv[kf * 16 + r] = s[r] * SCALE;
        }
        __builtin_amdgcn_s_setprio(0);

        if (kt * 64 + 63 > q0 + wid * 32) {  // diagonal tile: causal mask
#pragma unroll
          for (int kf = 0; kf < 2; ++kf)
#pragma unroll
            for (int r = 0; r < 16; ++r) {
              int kl = kf * 32 + (r & 3) + 8 * (r >> 2) + 4 * hi;
              if (kt * 64 + kl > qg) pv[kf * 16 + r] = -1e30f;
            }
        }

        float mt = pv[0];
#pragma unroll
        for (int i = 1; i < 32; ++i) mt = fmaxf(mt, pv[i]);
        mt = fmaxf(mt, __shfl_xor(mt, 32, 64));
        float mn = fmaxf(m_run, mt);
        float alpha = __expf(m_run - mn);
        float ls = 0.f;
#pragma unroll
        for (int i = 0; i < 32; ++i) { pv[i] = __expf(pv[i] - mn); ls += pv[i]; }
        ls += __shfl_xor(ls, 32, 64);
        l_run = l_run * alpha + ls;
        m_run = mn;
#pragma unroll
        for (int f = 0; f < 4; ++f)
#pragma unroll
          for (int r = 0; r < 16; ++r) oacc[f][r] *= alpha;

        // pack P -> PV B-operand (T12: cvt_pk + permlane32_swap)
        union PW { uint32_t w[4]; bf16x8 v; } pa[4];
#pragma unroll
        for (int ks = 0; ks < 4; ++ks) {
          uint32_t x0, x1, y0, y1;
          asm("v_cvt_pk_bf16_f32 %0, %1, %2" : "=v"(x0) : "v"(pv[8 * ks + 0]), "v"(pv[8 * ks + 1]));
          asm("v_cvt_pk_bf16_f32 %0, %1, %2" : "=v"(x1) : "v"(pv[8 * ks + 2]), "v"(pv[8 * ks + 3]));
          asm("v_cvt_pk_bf16_f32 %0, %1, %2" : "=v"(y0) : "v"(pv[8 * ks + 4]), "v"(pv[8 * ks + 5]));
          asm("v_cvt_pk_bf16_f32 %0, %1, %2" : "=v"(y1) : "v"(pv[8 * ks + 6]), "v"(pv[8 * ks + 7]));
          u32x2 r0 = __builtin_amdgcn_permlane32_swap(x0, y0, false, false);
          u32x2 r1 = __builtin_amdgcn_permlane32_swap(x1, y1, false, false);
          pa[ks].w[0] = r0.x; pa[ks].w[1] = r1.x; pa[ks].w[2] = r0.y; pa[ks].w[3] = r1.y;
        }

        __builtin_amdgcn_s_setprio(1);
#pragma unroll
        for (int ks = 0; ks < 4; ++ks) {
#pragma unroll
          for (int f = 0; f < 4; ++f) {
            int dv = f * 32 + l32;
            int c8 = (2 * ks + hi) ^ (dv & 7);
            bf16x8 vfr = *reinterpret_cast<const bf16x8*>(&v_lds[cur][dv * 64 + c8 * 8]);
            oacc[f] = __builtin_amdgcn_mfma_f32_32x32x16_bf16(vfr, pa[ks].v, oacc[f], 0, 0, 0);
          }
        }
        __builtin_amdgcn_s_setprio(0);
      }

      __syncthreads();
    }

    float inv_l = 1.0f / l_run;
    ushort* aorow = AO + (size_t)qg * HID + h * HD;
#pragma unroll
    for (int f = 0; f < 4; ++f)
#pragma unroll
      for (int g = 0; g < 4; ++g) {
        ushort4 o;
        o.x = f2bf(oacc[f][g * 4 + 0] * inv_l);
        o.y = f2bf(oacc[f][g * 4 + 1] * inv_l);
        o.z = f2bf(oacc[f][g * 4 + 2] * inv_l);
        o.w = f2bf(oacc[f][g * 4 + 3] * inv_l);
        *reinterpret_cast<ushort4*>(aorow + f * 32 + g * 8 + 4 * hi) = o;
      }
  }
}

// ---------------- launcher ----------------
extern "C" void kernel_launch(void* const* d_in, const int* in_sizes, int n_in,
                              void* d_out, int out_size, void* d_ws, size_t ws_size,
                              hipStream_t stream) {
  (void)in_sizes; (void)n_in; (void)out_size;
  const float* hs = (const float*)d_in[0];
  const float* Wq = (const float*)d_in[1];
  const float* Wk = (const float*)d_in[2];
  const float* Wv = (const float*)d_in[3];
  const float* Wo = (const float*)d_in[4];
  float* out = (float*)d_out;

  // workspace layout (bytes)
  char* ws = (char*)d_ws;
  const size_t OFF_HSB   = 0;                         // 2048*4096 bf16 = 16 MB
  const size_t OFF_WQKVT = OFF_HSB + 16777216;        // 6144*4096 bf16 = 48 MB
  const size_t OFF_WOT   = OFF_WQKVT + 50331648;      // 4096*4096 bf16 = 32 MB
  const size_t OFF_QKV   = OFF_WOT + 33554432;        // 2048*6144 bf16 = 24 MB
  const size_t OFF_VT    = OFF_QKV + 25165824;        // 8*128*2048 bf16 = 4 MB
  const size_t OFF_AO    = OFF_VT + 4194304;          // 2048*4096 bf16 = 16 MB
  if (ws_size < OFF_AO + 16777216) return;            // ~140 MB needed

  ushort* hsb   = (ushort*)(ws + OFF_HSB);
  ushort* WqkvT = (ushort*)(ws + OFF_WQKVT);
  ushort* WoT   = (ushort*)(ws + OFF_WOT);
  ushort* QKV   = (ushort*)(ws + OFF_QKV);
  ushort* Vt    = (ushort*)(ws + OFF_VT);
  ushort* AO    = (ushort*)(ws + OFF_AO);

  cast_f32_bf16<<<8192, 256, 0, stream>>>(hs, hsb, S_LEN * HID);
  transpose_cast<<<dim3(4096 / 32, 4096 / 32), 256, 0, stream>>>(Wq, WqkvT, HID, 4096);
  transpose_cast<<<dim3(1024 / 32, 4096 / 32), 256, 0, stream>>>(Wk, WqkvT + (size_t)4096 * HID, HID, 1024);
  transpose_cast<<<dim3(1024 / 32, 4096 / 32), 256, 0, stream>>>(Wv, WqkvT + (size_t)5120 * HID, HID, 1024);
  transpose_cast<<<dim3(4096 / 32, 4096 / 32), 256, 0, stream>>>(Wo, WoT, 4096, HID);

  gemm_8ph<true><<<dim3(QKV_N / 256, S_LEN / 256), 512, 0, stream>>>(hsb, WqkvT, QKV, QKV_N, HID);
  rope_kernel<<<(S_LEN * 40 * 8) / 256, 256, 0, stream>>>(QKV);
  transpose_v<<<dim3(S_LEN / 64, HD / 64, NKV), 256, 0, stream>>>(QKV, Vt);
  attn_kernel<<<256, 256, 0, stream>>>(QKV, Vt, AO);
  gemm_8ph<false><<<dim3(HID / 256, S_LEN / 256), 512, 0, stream>>>(AO, WoT, out, HID, HID);
}

// Round 12
// 362.027 us; speedup vs baseline: 1.1667x; 1.0148x over previous
//
#include <hip/hip_runtime.h>
#include <cstdint>
#include <cstddef>

typedef __attribute__((ext_vector_type(4))) float f32x4;
typedef __attribute__((ext_vector_type(16))) float f32x16;
typedef __attribute__((ext_vector_type(8))) short bf16x8;
typedef __attribute__((ext_vector_type(2))) unsigned int u32x2;

#define S_LEN   2048
#define HID     4096
#define NH      32
#define NKV     8
#define HD      128
#define QKV_N   6144   /* 4096 Q + 1024 K + 1024 V */

typedef const __attribute__((address_space(1))) unsigned int* gptr_t;
typedef __attribute__((address_space(3))) unsigned int* lptr_t;

__device__ __forceinline__ void gload_lds16(const void* g, void* l) {
  __builtin_amdgcn_global_load_lds((gptr_t)g, (lptr_t)l, 16, 0, 0);
}

__device__ __forceinline__ ushort f2bf(float f) {
  union { float f; uint32_t u; } v; v.f = f;
  uint32_t r = v.u + 0x7FFFu + ((v.u >> 16) & 1u);
  return (ushort)(r >> 16);
}
__device__ __forceinline__ float bf2f(ushort u) {
  union { uint32_t u; float f; } v; v.u = ((uint32_t)u) << 16;
  return v.f;
}

// ---------------- cast f32 -> bf16 (vectorized) ----------------
__global__ void cast_f32_bf16(const float* __restrict__ in, ushort* __restrict__ out, int n) {
  int i = (blockIdx.x * 256 + threadIdx.x) * 4;
  if (i >= n) return;
  float4 v = *reinterpret_cast<const float4*>(in + i);
  ushort4 o;
  o.x = f2bf(v.x); o.y = f2bf(v.y); o.z = f2bf(v.z); o.w = f2bf(v.w);
  *reinterpret_cast<ushort4*>(out + i) = o;
}

// ---------------- transpose + cast: in f32 [R][C] -> out bf16 [C][R] ----------------
__global__ void transpose_cast(const float* __restrict__ in, ushort* __restrict__ out, int R, int C) {
  __shared__ float t[32][33];
  int tx = threadIdx.x & 31, ty = threadIdx.x >> 5;  // 32 x 8
  int r0 = blockIdx.y * 32, c0 = blockIdx.x * 32;
#pragma unroll
  for (int i = 0; i < 32; i += 8)
    t[ty + i][tx] = in[(size_t)(r0 + ty + i) * C + c0 + tx];
  __syncthreads();
#pragma unroll
  for (int i = 0; i < 32; i += 8)
    out[(size_t)(c0 + ty + i) * R + r0 + tx] = f2bf(t[tx][ty + i]);
}

// ---------------- GEMM: C[M][N] = A[M][K] * B^T  (B stored [N][K]), bf16 in, fp32 acc ----------------
// m97 structure: 128x128 tile, BK=32, 4 waves (2x2), each wave 64x64 (4x4 frags of 16x16x32).
// Proven operating point (R6/R8: QKV ~130us / ~805 TF). Structural variants R5/R7/R10/R11
// all landed <= this; multi-block-per-CU overlap is what hides the barrier drain.
template <bool BF16_OUT>
__global__ __launch_bounds__(256, 4) void gemm_bt(
    const ushort* __restrict__ A, const ushort* __restrict__ B,
    void* __restrict__ Cp, int M, int N, int K) {
  __shared__ ushort a_lds[128 * 32];
  __shared__ ushort b_lds[128 * 32];
  const int tid = threadIdx.x;
  const int wid = tid >> 6, lane = tid & 63;
  const int l16 = lane & 15, lk = lane >> 4;
  const int wr = wid >> 1, wc = wid & 1;
  const size_t a_row0 = (size_t)blockIdx.y * 128;
  const size_t b_row0 = (size_t)blockIdx.x * 128;

  f32x4 acc[4][4] = {};
  const int pswz = lk ^ (l16 & 3) ^ ((l16 >> 2) & 1);

  for (int kt = 0; kt < K; kt += 32) {
    __syncthreads();
#pragma unroll
    for (int i = 0; i < 2; ++i) {
      int c = i * 256 + tid;
      int row = c >> 2, p = c & 3;
      int gch = p ^ (row & 3) ^ ((row >> 2) & 1);
      gload_lds16(A + (a_row0 + row) * K + kt + gch * 8, &a_lds[c * 8]);
      gload_lds16(B + (b_row0 + row) * K + kt + gch * 8, &b_lds[c * 8]);
    }
    __syncthreads();

    bf16x8 af[4], bf[4];
#pragma unroll
    for (int m = 0; m < 4; ++m) {
      int row = wr * 64 + m * 16 + l16;
      af[m] = *reinterpret_cast<const bf16x8*>(&a_lds[row * 32 + pswz * 8]);
    }
#pragma unroll
    for (int n = 0; n < 4; ++n) {
      int row = wc * 64 + n * 16 + l16;
      bf[n] = *reinterpret_cast<const bf16x8*>(&b_lds[row * 32 + pswz * 8]);
    }
#pragma unroll
    for (int m = 0; m < 4; ++m)
#pragma unroll
      for (int n = 0; n < 4; ++n)
        acc[m][n] = __builtin_amdgcn_mfma_f32_16x16x32_bf16(af[m], bf[n], acc[m][n], 0, 0, 0);
  }

#pragma unroll
  for (int m = 0; m < 4; ++m) {
    int row_b = wr * 64 + m * 16 + lk * 4;
#pragma unroll
    for (int n = 0; n < 4; ++n) {
      int col = (int)b_row0 + wc * 64 + n * 16 + l16;
#pragma unroll
      for (int r = 0; r < 4; ++r) {
        size_t row = a_row0 + row_b + r;
        if constexpr (BF16_OUT)
          ((ushort*)Cp)[row * N + col] = f2bf(acc[m][n][r]);
        else
          ((float*)Cp)[row * N + col] = acc[m][n][r];
      }
    }
  }
}

// ---------------- O-proj GEMM, K-split x2 in one launch (4 blocks/CU) ----------------
// 1024 blocks: kh = bid>>9 selects K-half [kh*2048, +2048); rem as (by,bx) over 16x32 tiles.
// Writes f32 partials P0/P1 (overlaid on dead hsb/WqkvT workspace); add_f32 reduces.
// Rationale (R8 counters): O-proj at 512 blocks = 2 blocks/CU was latency-starved
// (130us / 528 TF vs QKV's 3 blocks/CU at 805 TF). 4/CU restores the overlap.
__global__ __launch_bounds__(256, 4) void gemm_o_ks(
    const ushort* __restrict__ A, const ushort* __restrict__ B,
    float* __restrict__ P0, float* __restrict__ P1) {
  __shared__ ushort a_lds[128 * 32];
  __shared__ ushort b_lds[128 * 32];
  const int bid = blockIdx.x;
  const int kh = bid >> 9;
  const int rem = bid & 511;
  const size_t b_row0 = (size_t)(rem & 31) * 128;   // N/128 = 32
  const size_t a_row0 = (size_t)(rem >> 5) * 128;   // M/128 = 16
  const int k0 = kh * 2048, k1 = k0 + 2048;
  float* __restrict__ P = kh ? P1 : P0;
  const int tid = threadIdx.x;
  const int wid = tid >> 6, lane = tid & 63;
  const int l16 = lane & 15, lk = lane >> 4;
  const int wr = wid >> 1, wc = wid & 1;

  f32x4 acc[4][4] = {};
  const int pswz = lk ^ (l16 & 3) ^ ((l16 >> 2) & 1);

  for (int kt = k0; kt < k1; kt += 32) {
    __syncthreads();
#pragma unroll
    for (int i = 0; i < 2; ++i) {
      int c = i * 256 + tid;
      int row = c >> 2, p = c & 3;
      int gch = p ^ (row & 3) ^ ((row >> 2) & 1);
      gload_lds16(A + (a_row0 + row) * HID + kt + gch * 8, &a_lds[c * 8]);
      gload_lds16(B + (b_row0 + row) * HID + kt + gch * 8, &b_lds[c * 8]);
    }
    __syncthreads();

    bf16x8 af[4], bf[4];
#pragma unroll
    for (int m = 0; m < 4; ++m) {
      int row = wr * 64 + m * 16 + l16;
      af[m] = *reinterpret_cast<const bf16x8*>(&a_lds[row * 32 + pswz * 8]);
    }
#pragma unroll
    for (int n = 0; n < 4; ++n) {
      int row = wc * 64 + n * 16 + l16;
      bf[n] = *reinterpret_cast<const bf16x8*>(&b_lds[row * 32 + pswz * 8]);
    }
#pragma unroll
    for (int m = 0; m < 4; ++m)
#pragma unroll
      for (int n = 0; n < 4; ++n)
        acc[m][n] = __builtin_amdgcn_mfma_f32_16x16x32_bf16(af[m], bf[n], acc[m][n], 0, 0, 0);
  }

#pragma unroll
  for (int m = 0; m < 4; ++m) {
    int row_b = wr * 64 + m * 16 + lk * 4;
#pragma unroll
    for (int n = 0; n < 4; ++n) {
      int col = (int)b_row0 + wc * 64 + n * 16 + l16;
#pragma unroll
      for (int r = 0; r < 4; ++r)
        P[(a_row0 + row_b + r) * HID + col] = acc[m][n][r];
    }
  }
}

__global__ void add_f32(const float* __restrict__ a, const float* __restrict__ b,
                        float* __restrict__ o, int n) {
  int i = (blockIdx.x * 256 + threadIdx.x) * 4;
  if (i >= n) return;
  float4 x = *reinterpret_cast<const float4*>(a + i);
  float4 y = *reinterpret_cast<const float4*>(b + i);
  float4 z; z.x = x.x + y.x; z.y = x.y + y.y; z.z = x.z + y.z; z.w = x.w + y.w;
  *reinterpret_cast<float4*>(o + i) = z;
}

// ---------------- RoPE in-place on Q (cols 0..4095) and K (cols 4096..5119) of QKV ----------------
__global__ void rope_kernel(ushort* __restrict__ QKV) {
  int idx = blockIdx.x * 256 + threadIdx.x;  // 2048 * 40 * 8 threads
  int dg = idx & 7;
  int t = idx >> 3;
  int s = t / 40;
  int hh = t - s * 40;
  if (s >= S_LEN) return;
  int col = (hh < NH) ? hh * HD : HID + (hh - NH) * HD;
  ushort* base = QKV + (size_t)s * QKV_N + col + dg * 8;

  union U { uint4 v; ushort u[8]; };
  U L, H, OL, OH;
  L.v = *reinterpret_cast<const uint4*>(base);
  H.v = *reinterpret_cast<const uint4*>(base + 64);
  const float C0 = 13.287712379549449f / 64.0f;  // log2(10000)/64
#pragma unroll
  for (int j = 0; j < 8; ++j) {
    int d = dg * 8 + j;
    float invf = exp2f(-(float)d * C0);
    float ang = (float)s * invf;
    float sn, cs;
    sincosf(ang, &sn, &cs);
    float xl = bf2f(L.u[j]), xh = bf2f(H.u[j]);
    OL.u[j] = f2bf(xl * cs - xh * sn);
    OH.u[j] = f2bf(xh * cs + xl * sn);
  }
  *reinterpret_cast<uint4*>(base) = OL.v;
  *reinterpret_cast<uint4*>(base + 64) = OH.v;
}

// ---------------- V slice of QKV -> Vt[8][128][2048] ----------------
__global__ void transpose_v(const ushort* __restrict__ QKV, ushort* __restrict__ Vt) {
  __shared__ ushort t[64][65];
  int s0 = blockIdx.x * 64;
  int d0 = blockIdx.y * 64;
  int hkv = blockIdx.z;
  int tx = threadIdx.x & 63, ty = threadIdx.x >> 6;  // 64 x 4
#pragma unroll
  for (int i = 0; i < 64; i += 4)
    t[i + ty][tx] = QKV[(size_t)(s0 + i + ty) * QKV_N + HID + NKV * HD + hkv * HD + d0 + tx];
  __syncthreads();
#pragma unroll
  for (int i = 0; i < 64; i += 4)
    Vt[((size_t)hkv * HD + d0 + i + ty) * S_LEN + s0 + tx] = t[tx][i + ty];
}

// ---------------- flash attention: dual-panel 8-wave blocks, shared KV staging ----------------
// Grid = 256 blocks x 512 threads. h=(lin&7)*4+((lin>>3)&3) (XCD-local hkv), pr=lin>>5.
// Waves 0-3: q-panel 15-pr (128 rows); waves 4-7: q-panel pr. Panel pr's KV range is a
// subset of panel (15-pr)'s, so one staging stream serves both -> 2 waves/SIMD (vs 1 in
// the sequential-pair version) and ~25% less staging traffic. Per-wave gates skip tiles
// beyond a wave's causal range (barrier counts stay uniform).
__global__ __launch_bounds__(512, 2) void attn_kernel(
    const ushort* __restrict__ QKV, const ushort* __restrict__ Vt, ushort* __restrict__ AO) {
  constexpr float SCALE = 0.08838834764831845f;  // 1/sqrt(128)
  __shared__ ushort k_lds[2][64 * 128];   // [krow][128 d], 16B chunks XOR-swizzled by (row&7)
  __shared__ ushort v_lds[2][128 * 64];   // [d][64 s], 16B chunks XOR-swizzled by (row&7)

  const int lin = blockIdx.x;
  const int h = ((lin & 7) << 2) + ((lin >> 3) & 3);
  const int pr = lin >> 5;                // 0..7
  const int hkv = h >> 2;
  const int tid = threadIdx.x, w = tid >> 6, lane = tid & 63;
  const int l32 = lane & 31;
  const int hi = lane >> 5;
  const int qb = (w < 4) ? (15 - pr) : pr;
  const int q0w = qb * 128 + (w & 3) * 32;  // this wave's first q row
  const int qg = q0w + l32;                 // this lane's q row

  bf16x8 qf[8];
  {
    const ushort* qrow = QKV + (size_t)qg * QKV_N + h * HD + hi * 8;
#pragma unroll
    for (int ds = 0; ds < 8; ++ds)
      qf[ds] = *reinterpret_cast<const bf16x8*>(qrow + ds * 16);
  }

  float m_run = -1e30f, l_run = 0.f;
  f32x16 oacc[4] = {};   // oacc[f][r] = O[q=l32][d = f*32 + crow(r,hi)]

  auto stageKV = [&](int buf, int kt) {
#pragma unroll
    for (int i = 0; i < 2; ++i) {
      int c = i * 512 + tid;               // K: 1024 chunks
      int row = c >> 4, ch = c & 15;
      int sch = ch ^ (row & 7);
      gload_lds16(QKV + (size_t)(kt * 64 + row) * QKV_N + HID + hkv * HD + sch * 8,
                  &k_lds[buf][c * 8]);
    }
#pragma unroll
    for (int i = 0; i < 2; ++i) {
      int c = i * 512 + tid;               // V: 1024 chunks
      int row = c >> 3, ch = c & 7;
      int sch = ch ^ (row & 7);
      gload_lds16(Vt + ((size_t)hkv * HD + row) * S_LEN + (size_t)kt * 64 + sch * 8,
                  &v_lds[buf][c * 8]);
    }
  };

  const int NT = 34 - 2 * pr;   // big panel's tile count; small panel's range is a subset
  stageKV(0, 0);
  __syncthreads();

  for (int kt = 0; kt < NT; ++kt) {
    const int cur = kt & 1;
    if (kt + 1 < NT) stageKV(cur ^ 1, kt + 1);

    if (kt * 64 <= q0w + 31) {   // wave-uniform causal-range gate
      float pv[32];
      __builtin_amdgcn_s_setprio(1);
#pragma unroll
      for (int kf = 0; kf < 2; ++kf) {
        f32x16 s = {};
        int rk = kf * 32 + l32;
#pragma unroll
        for (int ds = 0; ds < 8; ++ds) {
          int c16 = (ds * 2 + hi) ^ (rk & 7);
          bf16x8 kfr = *reinterpret_cast<const bf16x8*>(&k_lds[cur][rk * 128 + c16 * 8]);
          s = __builtin_amdgcn_mfma_f32_32x32x16_bf16(kfr, qf[ds], s, 0, 0, 0);
        }
#pragma unroll
        for (int r = 0; r < 16; ++r) pv[kf * 16 + r] = s[r] * SCALE;
      }
      __builtin_amdgcn_s_setprio(0);

      if (kt * 64 + 63 > q0w) {  // diagonal tile: causal mask
#pragma unroll
        for (int kf = 0; kf < 2; ++kf)
#pragma unroll
          for (int r = 0; r < 16; ++r) {
            int kl = kf * 32 + (r & 3) + 8 * (r >> 2) + 4 * hi;
            if (kt * 64 + kl > qg) pv[kf * 16 + r] = -1e30f;
          }
      }

      float mt = pv[0];
#pragma unroll
      for (int i = 1; i < 32; ++i) mt = fmaxf(mt, pv[i]);
      mt = fmaxf(mt, __shfl_xor(mt, 32, 64));
      float mn = fmaxf(m_run, mt);
      float alpha = __expf(m_run - mn);
      float ls = 0.f;
#pragma unroll
      for (int i = 0; i < 32; ++i) { pv[i] = __expf(pv[i] - mn); ls += pv[i]; }
      ls += __shfl_xor(ls, 32, 64);
      l_run = l_run * alpha + ls;
      m_run = mn;
#pragma unroll
      for (int f = 0; f < 4; ++f)
#pragma unroll
        for (int r = 0; r < 16; ++r) oacc[f][r] *= alpha;

      // pack P -> PV B-operand (T12: cvt_pk + permlane32_swap)
      union PW { uint32_t w[4]; bf16x8 v; } pa[4];
#pragma unroll
      for (int ks = 0; ks < 4; ++ks) {
        uint32_t x0, x1, y0, y1;
        asm("v_cvt_pk_bf16_f32 %0, %1, %2" : "=v"(x0) : "v"(pv[8 * ks + 0]), "v"(pv[8 * ks + 1]));
        asm("v_cvt_pk_bf16_f32 %0, %1, %2" : "=v"(x1) : "v"(pv[8 * ks + 2]), "v"(pv[8 * ks + 3]));
        asm("v_cvt_pk_bf16_f32 %0, %1, %2" : "=v"(y0) : "v"(pv[8 * ks + 4]), "v"(pv[8 * ks + 5]));
        asm("v_cvt_pk_bf16_f32 %0, %1, %2" : "=v"(y1) : "v"(pv[8 * ks + 6]), "v"(pv[8 * ks + 7]));
        u32x2 r0 = __builtin_amdgcn_permlane32_swap(x0, y0, false, false);
        u32x2 r1 = __builtin_amdgcn_permlane32_swap(x1, y1, false, false);
        pa[ks].w[0] = r0.x; pa[ks].w[1] = r1.x; pa[ks].w[2] = r0.y; pa[ks].w[3] = r1.y;
      }

      __builtin_amdgcn_s_setprio(1);
#pragma unroll
      for (int ks = 0; ks < 4; ++ks) {
#pragma unroll
        for (int f = 0; f < 4; ++f) {
          int dv = f * 32 + l32;
          int c8 = (2 * ks + hi) ^ (dv & 7);
          bf16x8 vfr = *reinterpret_cast<const bf16x8*>(&v_lds[cur][dv * 64 + c8 * 8]);
          oacc[f] = __builtin_amdgcn_mfma_f32_32x32x16_bf16(vfr, pa[ks].v, oacc[f], 0, 0, 0);
        }
      }
      __builtin_amdgcn_s_setprio(0);
    }

    __syncthreads();
  }

  float inv_l = 1.0f / l_run;
  ushort* aorow = AO + (size_t)qg * HID + h * HD;
#pragma unroll
  for (int f = 0; f < 4; ++f)
#pragma unroll
    for (int g = 0; g < 4; ++g) {
      ushort4 o;
      o.x = f2bf(oacc[f][g * 4 + 0] * inv_l);
      o.y = f2bf(oacc[f][g * 4 + 1] * inv_l);
      o.z = f2bf(oacc[f][g * 4 + 2] * inv_l);
      o.w = f2bf(oacc[f][g * 4 + 3] * inv_l);
      *reinterpret_cast<ushort4*>(aorow + f * 32 + g * 8 + 4 * hi) = o;
    }
}

// ---------------- launcher ----------------
extern "C" void kernel_launch(void* const* d_in, const int* in_sizes, int n_in,
                              void* d_out, int out_size, void* d_ws, size_t ws_size,
                              hipStream_t stream) {
  (void)in_sizes; (void)n_in; (void)out_size;
  const float* hs = (const float*)d_in[0];
  const float* Wq = (const float*)d_in[1];
  const float* Wk = (const float*)d_in[2];
  const float* Wv = (const float*)d_in[3];
  const float* Wo = (const float*)d_in[4];
  float* out = (float*)d_out;

  // workspace layout (bytes)
  char* ws = (char*)d_ws;
  const size_t OFF_HSB   = 0;                         // 2048*4096 bf16 = 16 MB
  const size_t OFF_WQKVT = OFF_HSB + 16777216;        // 6144*4096 bf16 = 48 MB
  const size_t OFF_WOT   = OFF_WQKVT + 50331648;      // 4096*4096 bf16 = 32 MB
  const size_t OFF_QKV   = OFF_WOT + 33554432;        // 2048*6144 bf16 = 24 MB
  const size_t OFF_VT    = OFF_QKV + 25165824;        // 8*128*2048 bf16 = 4 MB
  const size_t OFF_AO    = OFF_VT + 4194304;          // 2048*4096 bf16 = 16 MB
  if (ws_size < OFF_AO + 16777216) return;            // ~140 MB needed

  ushort* hsb   = (ushort*)(ws + OFF_HSB);
  ushort* WqkvT = (ushort*)(ws + OFF_WQKVT);
  ushort* WoT   = (ushort*)(ws + OFF_WOT);
  ushort* QKV   = (ushort*)(ws + OFF_QKV);
  ushort* Vt    = (ushort*)(ws + OFF_VT);
  ushort* AO    = (ushort*)(ws + OFF_AO);
  // f32 partials for the K-split O-proj, overlaid on hsb+WqkvT (both dead after QKV GEMM)
  float* P0 = (float*)(ws + 0);                       // 32 MB
  float* P1 = (float*)(ws + 33554432);                // 32 MB

  cast_f32_bf16<<<8192, 256, 0, stream>>>(hs, hsb, S_LEN * HID);
  transpose_cast<<<dim3(4096 / 32, 4096 / 32), 256, 0, stream>>>(Wq, WqkvT, HID, 4096);
  transpose_cast<<<dim3(1024 / 32, 4096 / 32), 256, 0, stream>>>(Wk, WqkvT + (size_t)4096 * HID, HID, 1024);
  transpose_cast<<<dim3(1024 / 32, 4096 / 32), 256, 0, stream>>>(Wv, WqkvT + (size_t)5120 * HID, HID, 1024);
  transpose_cast<<<dim3(4096 / 32, 4096 / 32), 256, 0, stream>>>(Wo, WoT, 4096, HID);

  gemm_bt<true><<<dim3(QKV_N / 128, S_LEN / 128), 256, 0, stream>>>(hsb, WqkvT, QKV, S_LEN, QKV_N, HID);
  rope_kernel<<<(S_LEN * 40 * 8) / 256, 256, 0, stream>>>(QKV);
  transpose_v<<<dim3(S_LEN / 64, HD / 64, NKV), 256, 0, stream>>>(QKV, Vt);
  attn_kernel<<<256, 512, 0, stream>>>(QKV, Vt, AO);
  gemm_o_ks<<<1024, 256, 0, stream>>>(AO, WoT, P0, P1);
  add_f32<<<8192, 256, 0, stream>>>(P0, P1, out, S_LEN * HID);
}

// Round 13
// 351.978 us; speedup vs baseline: 1.2000x; 1.0286x over previous
//
#include <hip/hip_runtime.h>
#include <cstdint>
#include <cstddef>

typedef __attribute__((ext_vector_type(4))) float f32x4;
typedef __attribute__((ext_vector_type(16))) float f32x16;
typedef __attribute__((ext_vector_type(8))) short bf16x8;
typedef __attribute__((ext_vector_type(2))) unsigned int u32x2;

#define S_LEN   2048
#define HID     4096
#define NH      32
#define NKV     8
#define HD      128
#define QKV_N   6144   /* 4096 Q + 1024 K + 1024 V */

typedef const __attribute__((address_space(1))) unsigned int* gptr_t;
typedef __attribute__((address_space(3))) unsigned int* lptr_t;

__device__ __forceinline__ void gload_lds16(const void* g, void* l) {
  __builtin_amdgcn_global_load_lds((gptr_t)g, (lptr_t)l, 16, 0, 0);
}

__device__ __forceinline__ ushort f2bf(float f) {
  union { float f; uint32_t u; } v; v.f = f;
  uint32_t r = v.u + 0x7FFFu + ((v.u >> 16) & 1u);
  return (ushort)(r >> 16);
}
__device__ __forceinline__ float bf2f(ushort u) {
  union { uint32_t u; float f; } v; v.u = ((uint32_t)u) << 16;
  return v.f;
}

// ---------------- cast f32 -> bf16 (vectorized) ----------------
__global__ void cast_f32_bf16(const float* __restrict__ in, ushort* __restrict__ out, int n) {
  int i = (blockIdx.x * 256 + threadIdx.x) * 4;
  if (i >= n) return;
  float4 v = *reinterpret_cast<const float4*>(in + i);
  ushort4 o;
  o.x = f2bf(v.x); o.y = f2bf(v.y); o.z = f2bf(v.z); o.w = f2bf(v.w);
  *reinterpret_cast<ushort4*>(out + i) = o;
}

// ---------------- all 4 weight transposes in one launch (range-partitioned) ----------------
// Wq[4096][4096]->WqkvT[0..4096), Wk[4096][1024]->WqkvT+4096*HID, Wv->+5120*HID,
// Wo[4096][4096]->WoT. All sources have R=4096 rows; transpose+cast 32x32 tiles.
__global__ void transpose_cast_all(const float* __restrict__ Wq, const float* __restrict__ Wk,
                                   const float* __restrict__ Wv, const float* __restrict__ Wo,
                                   ushort* __restrict__ WqkvT, ushort* __restrict__ WoT) {
  __shared__ float t[32][33];
  int id = blockIdx.x;
  const float* src; ushort* dst; int C, local;
  if (id < 16384)        { src = Wq; dst = WqkvT;                           C = 4096; local = id; }
  else if (id < 20480)   { src = Wk; dst = WqkvT + (size_t)4096 * HID;      C = 1024; local = id - 16384; }
  else if (id < 24576)   { src = Wv; dst = WqkvT + (size_t)5120 * HID;      C = 1024; local = id - 20480; }
  else                   { src = Wo; dst = WoT;                             C = 4096; local = id - 24576; }
  const int cb = C >> 5;
  int bx = local % cb, by = local / cb;
  int tx = threadIdx.x & 31, ty = threadIdx.x >> 5;  // 32 x 8
  int r0 = by * 32, c0 = bx * 32;
#pragma unroll
  for (int i = 0; i < 32; i += 8)
    t[ty + i][tx] = src[(size_t)(r0 + ty + i) * C + c0 + tx];
  __syncthreads();
#pragma unroll
  for (int i = 0; i < 32; i += 8)
    dst[(size_t)(c0 + ty + i) * 4096 + r0 + tx] = f2bf(t[tx][ty + i]);
}

// ---------------- GEMM: C[M][N] = A[M][K] * B^T  (B stored [N][K]), bf16 in, fp32 acc ----------------
// m97 structure: 128x128 tile, BK=32, 4 waves (2x2), each wave 64x64 (4x4 frags of 16x16x32).
// Proven operating point (R6/R8/R12: QKV ~130us / ~805 TF). Structural variants
// R5/R7/R10/R11 all landed <= this; multi-block-per-CU overlap hides the barrier drain.
template <bool BF16_OUT>
__global__ __launch_bounds__(256, 4) void gemm_bt(
    const ushort* __restrict__ A, const ushort* __restrict__ B,
    void* __restrict__ Cp, int M, int N, int K) {
  __shared__ ushort a_lds[128 * 32];
  __shared__ ushort b_lds[128 * 32];
  const int tid = threadIdx.x;
  const int wid = tid >> 6, lane = tid & 63;
  const int l16 = lane & 15, lk = lane >> 4;
  const int wr = wid >> 1, wc = wid & 1;
  const size_t a_row0 = (size_t)blockIdx.y * 128;
  const size_t b_row0 = (size_t)blockIdx.x * 128;

  f32x4 acc[4][4] = {};
  const int pswz = lk ^ (l16 & 3) ^ ((l16 >> 2) & 1);

  for (int kt = 0; kt < K; kt += 32) {
    __syncthreads();
#pragma unroll
    for (int i = 0; i < 2; ++i) {
      int c = i * 256 + tid;
      int row = c >> 2, p = c & 3;
      int gch = p ^ (row & 3) ^ ((row >> 2) & 1);
      gload_lds16(A + (a_row0 + row) * K + kt + gch * 8, &a_lds[c * 8]);
      gload_lds16(B + (b_row0 + row) * K + kt + gch * 8, &b_lds[c * 8]);
    }
    __syncthreads();

    bf16x8 af[4], bf[4];
#pragma unroll
    for (int m = 0; m < 4; ++m) {
      int row = wr * 64 + m * 16 + l16;
      af[m] = *reinterpret_cast<const bf16x8*>(&a_lds[row * 32 + pswz * 8]);
    }
#pragma unroll
    for (int n = 0; n < 4; ++n) {
      int row = wc * 64 + n * 16 + l16;
      bf[n] = *reinterpret_cast<const bf16x8*>(&b_lds[row * 32 + pswz * 8]);
    }
#pragma unroll
    for (int m = 0; m < 4; ++m)
#pragma unroll
      for (int n = 0; n < 4; ++n)
        acc[m][n] = __builtin_amdgcn_mfma_f32_16x16x32_bf16(af[m], bf[n], acc[m][n], 0, 0, 0);
  }

#pragma unroll
  for (int m = 0; m < 4; ++m) {
    int row_b = wr * 64 + m * 16 + lk * 4;
#pragma unroll
    for (int n = 0; n < 4; ++n) {
      int col = (int)b_row0 + wc * 64 + n * 16 + l16;
#pragma unroll
      for (int r = 0; r < 4; ++r) {
        size_t row = a_row0 + row_b + r;
        if constexpr (BF16_OUT)
          ((ushort*)Cp)[row * N + col] = f2bf(acc[m][n][r]);
        else
          ((float*)Cp)[row * N + col] = acc[m][n][r];
      }
    }
  }
}

// ---------------- O-proj GEMM, K-split x2 in one launch (4 blocks/CU) ----------------
// 1024 blocks: kh = bid>>9 selects K-half; rem over 16x32 tiles. f32 partials P0/P1
// (overlaid on dead hsb/WqkvT workspace); add_f32 reduces. Rationale (R8): O-proj at
// 512 blocks = 2/CU was latency-starved; 4/CU restores the inter-block overlap.
__global__ __launch_bounds__(256, 4) void gemm_o_ks(
    const ushort* __restrict__ A, const ushort* __restrict__ B,
    float* __restrict__ P0, float* __restrict__ P1) {
  __shared__ ushort a_lds[128 * 32];
  __shared__ ushort b_lds[128 * 32];
  const int bid = blockIdx.x;
  const int kh = bid >> 9;
  const int rem = bid & 511;
  const size_t b_row0 = (size_t)(rem & 31) * 128;   // N/128 = 32
  const size_t a_row0 = (size_t)(rem >> 5) * 128;   // M/128 = 16
  const int k0 = kh * 2048, k1 = k0 + 2048;
  float* __restrict__ P = kh ? P1 : P0;
  const int tid = threadIdx.x;
  const int wid = tid >> 6, lane = tid & 63;
  const int l16 = lane & 15, lk = lane >> 4;
  const int wr = wid >> 1, wc = wid & 1;

  f32x4 acc[4][4] = {};
  const int pswz = lk ^ (l16 & 3) ^ ((l16 >> 2) & 1);

  for (int kt = k0; kt < k1; kt += 32) {
    __syncthreads();
#pragma unroll
    for (int i = 0; i < 2; ++i) {
      int c = i * 256 + tid;
      int row = c >> 2, p = c & 3;
      int gch = p ^ (row & 3) ^ ((row >> 2) & 1);
      gload_lds16(A + (a_row0 + row) * HID + kt + gch * 8, &a_lds[c * 8]);
      gload_lds16(B + (b_row0 + row) * HID + kt + gch * 8, &b_lds[c * 8]);
    }
    __syncthreads();

    bf16x8 af[4], bf[4];
#pragma unroll
    for (int m = 0; m < 4; ++m) {
      int row = wr * 64 + m * 16 + l16;
      af[m] = *reinterpret_cast<const bf16x8*>(&a_lds[row * 32 + pswz * 8]);
    }
#pragma unroll
    for (int n = 0; n < 4; ++n) {
      int row = wc * 64 + n * 16 + l16;
      bf[n] = *reinterpret_cast<const bf16x8*>(&b_lds[row * 32 + pswz * 8]);
    }
#pragma unroll
    for (int m = 0; m < 4; ++m)
#pragma unroll
      for (int n = 0; n < 4; ++n)
        acc[m][n] = __builtin_amdgcn_mfma_f32_16x16x32_bf16(af[m], bf[n], acc[m][n], 0, 0, 0);
  }

#pragma unroll
  for (int m = 0; m < 4; ++m) {
    int row_b = wr * 64 + m * 16 + lk * 4;
#pragma unroll
    for (int n = 0; n < 4; ++n) {
      int col = (int)b_row0 + wc * 64 + n * 16 + l16;
#pragma unroll
      for (int r = 0; r < 4; ++r)
        P[(a_row0 + row_b + r) * HID + col] = acc[m][n][r];
    }
  }
}

__global__ void add_f32(const float* __restrict__ a, const float* __restrict__ b,
                        float* __restrict__ o, int n) {
  int i = (blockIdx.x * 256 + threadIdx.x) * 4;
  if (i >= n) return;
  float4 x = *reinterpret_cast<const float4*>(a + i);
  float4 y = *reinterpret_cast<const float4*>(b + i);
  float4 z; z.x = x.x + y.x; z.y = x.y + y.y; z.z = x.z + y.z; z.w = x.w + y.w;
  *reinterpret_cast<float4*>(o + i) = z;
}

// ---------------- fused RoPE (Q/K cols) + V transpose — independent QKV regions ----------------
// Blocks [0,2560): rope on QKV cols 0..5119. Blocks [2560,3072): V slice -> Vt[8][128][2048].
__global__ void rope_and_tv(ushort* __restrict__ QKV, ushort* __restrict__ Vt) {
  if (blockIdx.x < 2560) {
    int idx = blockIdx.x * 256 + threadIdx.x;  // 2048 * 40 * 8 threads
    int dg = idx & 7;
    int t = idx >> 3;
    int s = t / 40;
    int hh = t - s * 40;
    if (s >= S_LEN) return;
    int col = (hh < NH) ? hh * HD : HID + (hh - NH) * HD;
    ushort* base = QKV + (size_t)s * QKV_N + col + dg * 8;

    union U { uint4 v; ushort u[8]; };
    U L, H, OL, OH;
    L.v = *reinterpret_cast<const uint4*>(base);
    H.v = *reinterpret_cast<const uint4*>(base + 64);
    const float C0 = 13.287712379549449f / 64.0f;  // log2(10000)/64
#pragma unroll
    for (int j = 0; j < 8; ++j) {
      int d = dg * 8 + j;
      float invf = exp2f(-(float)d * C0);
      float ang = (float)s * invf;
      float sn, cs;
      sincosf(ang, &sn, &cs);
      float xl = bf2f(L.u[j]), xh = bf2f(H.u[j]);
      OL.u[j] = f2bf(xl * cs - xh * sn);
      OH.u[j] = f2bf(xh * cs + xl * sn);
    }
    *reinterpret_cast<uint4*>(base) = OL.v;
    *reinterpret_cast<uint4*>(base + 64) = OH.v;
  } else {
    __shared__ ushort t[64][65];
    int local = blockIdx.x - 2560;             // 32 s-tiles x 2 d-tiles x 8 hkv
    int s0 = (local & 31) * 64;
    int d0 = ((local >> 5) & 1) * 64;
    int hkv = local >> 6;
    int tx = threadIdx.x & 63, ty = threadIdx.x >> 6;  // 64 x 4
#pragma unroll
    for (int i = 0; i < 64; i += 4)
      t[i + ty][tx] = QKV[(size_t)(s0 + i + ty) * QKV_N + HID + NKV * HD + hkv * HD + d0 + tx];
    __syncthreads();
#pragma unroll
    for (int i = 0; i < 64; i += 4)
      Vt[((size_t)hkv * HD + d0 + i + ty) * S_LEN + s0 + tx] = t[tx][i + ty];
  }
}

// ---------------- flash attention: swapped-QK^T 32x32 MFMA, in-register softmax ----------------
// R8-proven version. Grid = 256 blocks (one full-chip round). h=(lin&7)*4+((lin>>3)&3),
// p=lin>>5; block does q-panels {p, 15-p} sequentially -> uniform 34 KV-tiles;
// XCD-local KV (1MB per hkv, fits 4MB XCD L2).
__global__ __launch_bounds__(256, 2) void attn_kernel(
    const ushort* __restrict__ QKV, const ushort* __restrict__ Vt, ushort* __restrict__ AO) {
  constexpr float SCALE = 0.08838834764831845f;  // 1/sqrt(128)
  __shared__ ushort k_lds[2][64 * 128];   // [krow][128 d], 16B chunks XOR-swizzled by (row&7)
  __shared__ ushort v_lds[2][128 * 64];   // [d][64 s], 16B chunks XOR-swizzled by (row&7)

  const int lin = blockIdx.x;
  const int h = ((lin & 7) << 2) + ((lin >> 3) & 3);
  const int p = lin >> 5;                 // 0..7
  const int hkv = h >> 2;
  const int tid = threadIdx.x, wid = tid >> 6, lane = tid & 63;
  const int l32 = lane & 31;
  const int hi = lane >> 5;

  auto stageKV = [&](int buf, int kt) {
#pragma unroll
    for (int i = 0; i < 4; ++i) {
      int c = i * 256 + wid * 64 + lane;
      int row = c >> 4, ch = c & 15;
      int sch = ch ^ (row & 7);
      gload_lds16(QKV + (size_t)(kt * 64 + row) * QKV_N + HID + hkv * HD + sch * 8,
                  &k_lds[buf][c * 8]);
    }
#pragma unroll
    for (int i = 0; i < 4; ++i) {
      int c = i * 256 + wid * 64 + lane;
      int row = c >> 3, ch = c & 7;
      int sch = ch ^ (row & 7);
      gload_lds16(Vt + ((size_t)hkv * HD + row) * S_LEN + (size_t)kt * 64 + sch * 8,
                  &v_lds[buf][c * 8]);
    }
  };

  for (int pi = 0; pi < 2; ++pi) {
    const int qb = pi ? (15 - p) : p;
    const int q0 = qb * 128;
    const int qg = q0 + wid * 32 + l32;   // this lane's q row

    bf16x8 qf[8];
    {
      const ushort* qrow = QKV + (size_t)qg * QKV_N + h * HD + hi * 8;
#pragma unroll
      for (int ds = 0; ds < 8; ++ds)
        qf[ds] = *reinterpret_cast<const bf16x8*>(qrow + ds * 16);
    }

    float m_run = -1e30f, l_run = 0.f;
    f32x16 oacc[4] = {};   // oacc[f][r] = O[q=l32][d = f*32 + crow(r,hi)]

    stageKV(0, 0);
    __syncthreads();

    const int nt = 2 * qb + 2;
    for (int kt = 0; kt < nt; ++kt) {
      const int cur = kt & 1;
      if (kt + 1 < nt) stageKV(cur ^ 1, kt + 1);

      if (kt * 64 <= q0 + wid * 32 + 31) {
        float pv[32];
        __builtin_amdgcn_s_setprio(1);
#pragma unroll
        for (int kf = 0; kf < 2; ++kf) {
          f32x16 s = {};
          int rk = kf * 32 + l32;
#pragma unroll
          for (int ds = 0; ds < 8; ++ds) {
            int c16 = (ds * 2 + hi) ^ (rk & 7);
            bf16x8 kfr = *reinterpret_cast<const bf16x8*>(&k_lds[cur][rk * 128 + c16 * 8]);
            s = __builtin_amdgcn_mfma_f32_32x32x16_bf16(kfr, qf[ds], s, 0, 0, 0);
          }
#pragma unroll
          for (int r = 0; r < 16; ++r) pv[kf * 16 + r] = s[r] * SCALE;
        }
        __builtin_amdgcn_s_setprio(0);

        if (kt * 64 + 63 > q0 + wid * 32) {  // diagonal tile: causal mask
#pragma unroll
          for (int kf = 0; kf < 2; ++kf)
#pragma unroll
            for (int r = 0; r < 16; ++r) {
              int kl = kf * 32 + (r & 3) + 8 * (r >> 2) + 4 * hi;
              if (kt * 64 + kl > qg) pv[kf * 16 + r] = -1e30f;
            }
        }

        float mt = pv[0];
#pragma unroll
        for (int i = 1; i < 32; ++i) mt = fmaxf(mt, pv[i]);
        mt = fmaxf(mt, __shfl_xor(mt, 32, 64));
        float mn = fmaxf(m_run, mt);
        float alpha = __expf(m_run - mn);
        float ls = 0.f;
#pragma unroll
        for (int i = 0; i < 32; ++i) { pv[i] = __expf(pv[i] - mn); ls += pv[i]; }
        ls += __shfl_xor(ls, 32, 64);
        l_run = l_run * alpha + ls;
        m_run = mn;
#pragma unroll
        for (int f = 0; f < 4; ++f)
#pragma unroll
          for (int r = 0; r < 16; ++r) oacc[f][r] *= alpha;

        // pack P -> PV B-operand (T12: cvt_pk + permlane32_swap)
        union PW { uint32_t w[4]; bf16x8 v; } pa[4];
#pragma unroll
        for (int ks = 0; ks < 4; ++ks) {
          uint32_t x0, x1, y0, y1;
          asm("v_cvt_pk_bf16_f32 %0, %1, %2" : "=v"(x0) : "v"(pv[8 * ks + 0]), "v"(pv[8 * ks + 1]));
          asm("v_cvt_pk_bf16_f32 %0, %1, %2" : "=v"(x1) : "v"(pv[8 * ks + 2]), "v"(pv[8 * ks + 3]));
          asm("v_cvt_pk_bf16_f32 %0, %1, %2" : "=v"(y0) : "v"(pv[8 * ks + 4]), "v"(pv[8 * ks + 5]));
          asm("v_cvt_pk_bf16_f32 %0, %1, %2" : "=v"(y1) : "v"(pv[8 * ks + 6]), "v"(pv[8 * ks + 7]));
          u32x2 r0 = __builtin_amdgcn_permlane32_swap(x0, y0, false, false);
          u32x2 r1 = __builtin_amdgcn_permlane32_swap(x1, y1, false, false);
          pa[ks].w[0] = r0.x; pa[ks].w[1] = r1.x; pa[ks].w[2] = r0.y; pa[ks].w[3] = r1.y;
        }

        __builtin_amdgcn_s_setprio(1);
#pragma unroll
        for (int ks = 0; ks < 4; ++ks) {
#pragma unroll
          for (int f = 0; f < 4; ++f) {
            int dv = f * 32 + l32;
            int c8 = (2 * ks + hi) ^ (dv & 7);
            bf16x8 vfr = *reinterpret_cast<const bf16x8*>(&v_lds[cur][dv * 64 + c8 * 8]);
            oacc[f] = __builtin_amdgcn_mfma_f32_32x32x16_bf16(vfr, pa[ks].v, oacc[f], 0, 0, 0);
          }
        }
        __builtin_amdgcn_s_setprio(0);
      }

      __syncthreads();
    }

    float inv_l = 1.0f / l_run;
    ushort* aorow = AO + (size_t)qg * HID + h * HD;
#pragma unroll
    for (int f = 0; f < 4; ++f)
#pragma unroll
      for (int g = 0; g < 4; ++g) {
        ushort4 o;
        o.x = f2bf(oacc[f][g * 4 + 0] * inv_l);
        o.y = f2bf(oacc[f][g * 4 + 1] * inv_l);
        o.z = f2bf(oacc[f][g * 4 + 2] * inv_l);
        o.w = f2bf(oacc[f][g * 4 + 3] * inv_l);
        *reinterpret_cast<ushort4*>(aorow + f * 32 + g * 8 + 4 * hi) = o;
      }
  }
}

// ---------------- launcher ----------------
extern "C" void kernel_launch(void* const* d_in, const int* in_sizes, int n_in,
                              void* d_out, int out_size, void* d_ws, size_t ws_size,
                              hipStream_t stream) {
  (void)in_sizes; (void)n_in; (void)out_size;
  const float* hs = (const float*)d_in[0];
  const float* Wq = (const float*)d_in[1];
  const float* Wk = (const float*)d_in[2];
  const float* Wv = (const float*)d_in[3];
  const float* Wo = (const float*)d_in[4];
  float* out = (float*)d_out;

  // workspace layout (bytes)
  char* ws = (char*)d_ws;
  const size_t OFF_HSB   = 0;                         // 2048*4096 bf16 = 16 MB
  const size_t OFF_WQKVT = OFF_HSB + 16777216;        // 6144*4096 bf16 = 48 MB
  const size_t OFF_WOT   = OFF_WQKVT + 50331648;      // 4096*4096 bf16 = 32 MB
  const size_t OFF_QKV   = OFF_WOT + 33554432;        // 2048*6144 bf16 = 24 MB
  const size_t OFF_VT    = OFF_QKV + 25165824;        // 8*128*2048 bf16 = 4 MB
  const size_t OFF_AO    = OFF_VT + 4194304;          // 2048*4096 bf16 = 16 MB
  if (ws_size < OFF_AO + 16777216) return;            // ~140 MB needed

  ushort* hsb   = (ushort*)(ws + OFF_HSB);
  ushort* WqkvT = (ushort*)(ws + OFF_WQKVT);
  ushort* WoT   = (ushort*)(ws + OFF_WOT);
  ushort* QKV   = (ushort*)(ws + OFF_QKV);
  ushort* Vt    = (ushort*)(ws + OFF_VT);
  ushort* AO    = (ushort*)(ws + OFF_AO);
  // f32 partials for the K-split O-proj, overlaid on hsb+WqkvT (both dead after QKV GEMM)
  float* P0 = (float*)(ws + 0);                       // 32 MB
  float* P1 = (float*)(ws + 33554432);                // 32 MB

  cast_f32_bf16<<<8192, 256, 0, stream>>>(hs, hsb, S_LEN * HID);
  transpose_cast_all<<<40960, 256, 0, stream>>>(Wq, Wk, Wv, Wo, WqkvT, WoT);

  gemm_bt<true><<<dim3(QKV_N / 128, S_LEN / 128), 256, 0, stream>>>(hsb, WqkvT, QKV, S_LEN, QKV_N, HID);
  rope_and_tv<<<3072, 256, 0, stream>>>(QKV, Vt);
  attn_kernel<<<256, 256, 0, stream>>>(QKV, Vt, AO);
  gemm_o_ks<<<1024, 256, 0, stream>>>(AO, WoT, P0, P1);
  add_f32<<<8192, 256, 0, stream>>>(P0, P1, out, S_LEN * HID);
}

// Round 14
// 330.203 us; speedup vs baseline: 1.2792x; 1.0659x over previous
//
#include <hip/hip_runtime.h>
#include <cstdint>
#include <cstddef>

typedef __attribute__((ext_vector_type(4))) float f32x4;
typedef __attribute__((ext_vector_type(16))) float f32x16;
typedef __attribute__((ext_vector_type(8))) short bf16x8;
typedef __attribute__((ext_vector_type(2))) unsigned int u32x2;

#define S_LEN   2048
#define HID     4096
#define NH      32
#define NKV     8
#define HD      128
#define QKV_N   6144   /* 4096 Q + 1024 K + 1024 V */

typedef const __attribute__((address_space(1))) unsigned int* gptr_t;
typedef __attribute__((address_space(3))) unsigned int* lptr_t;

__device__ __forceinline__ void gload_lds16(const void* g, void* l) {
  __builtin_amdgcn_global_load_lds((gptr_t)g, (lptr_t)l, 16, 0, 0);
}

__device__ __forceinline__ ushort f2bf(float f) {
  union { float f; uint32_t u; } v; v.f = f;
  uint32_t r = v.u + 0x7FFFu + ((v.u >> 16) & 1u);
  return (ushort)(r >> 16);
}
__device__ __forceinline__ float bf2f(ushort u) {
  union { uint32_t u; float f; } v; v.u = ((uint32_t)u) << 16;
  return v.f;
}

// ---------------- fused prep: hs cast + all 4 weight transposes (one launch) ----------------
// Blocks [0,8192): cast hs f32->bf16 (1024 elem/block). Blocks [8192,49152): 32x32
// transpose+cast tiles: Wq -> WqkvT[0..4096), Wk -> +4096*HID, Wv -> +5120*HID, Wo -> WoT.
__global__ void prep_all(const float* __restrict__ hs,
                         const float* __restrict__ Wq, const float* __restrict__ Wk,
                         const float* __restrict__ Wv, const float* __restrict__ Wo,
                         ushort* __restrict__ hsb,
                         ushort* __restrict__ WqkvT, ushort* __restrict__ WoT) {
  int id = blockIdx.x;
  if (id < 8192) {
    int i = (id * 256 + (int)threadIdx.x) * 4;
    float4 v = *reinterpret_cast<const float4*>(hs + i);
    ushort4 o;
    o.x = f2bf(v.x); o.y = f2bf(v.y); o.z = f2bf(v.z); o.w = f2bf(v.w);
    *reinterpret_cast<ushort4*>(hsb + i) = o;
    return;
  }
  __shared__ float t[32][33];
  id -= 8192;
  const float* src; ushort* dst; int C, local;
  if (id < 16384)        { src = Wq; dst = WqkvT;                      C = 4096; local = id; }
  else if (id < 20480)   { src = Wk; dst = WqkvT + (size_t)4096 * HID; C = 1024; local = id - 16384; }
  else if (id < 24576)   { src = Wv; dst = WqkvT + (size_t)5120 * HID; C = 1024; local = id - 20480; }
  else                   { src = Wo; dst = WoT;                        C = 4096; local = id - 24576; }
  const int cb = C >> 5;
  int bx = local % cb, by = local / cb;
  int tx = threadIdx.x & 31, ty = threadIdx.x >> 5;  // 32 x 8
  int r0 = by * 32, c0 = bx * 32;
#pragma unroll
  for (int i = 0; i < 32; i += 8)
    t[ty + i][tx] = src[(size_t)(r0 + ty + i) * C + c0 + tx];
  __syncthreads();
#pragma unroll
  for (int i = 0; i < 32; i += 8)
    dst[(size_t)(c0 + ty + i) * 4096 + r0 + tx] = f2bf(t[tx][ty + i]);
}

// ---------------- GEMM: C[M][N] = A[M][K] * B^T  (B stored [N][K]), bf16 in, fp32 acc ----------------
// m97 structure, BK=64: 128x128 tile, 4 waves (2x2), 32 MFMA per barrier pair (was 16 at
// BK=32) -> halves the vmcnt(0)-drain/barrier events that bound the BK=32 version
// (R13: MfmaUtil 34.5, VALUBusy 14 -> ~50% cycles in the drain). LDS 32KB, still
// resource-room for 4 blocks/CU (grid 3/CU is the binder). Chunk-XOR ch^(row&7) on
// stage source + fragment reads (8 chunks/row, 2-way = free; proven in attn staging).
// Frags read per K-step to keep VGPR ~115 < 128 (no spill at launch_bounds(256,4)).
template <bool BF16_OUT>
__global__ __launch_bounds__(256, 4) void gemm_bt(
    const ushort* __restrict__ A, const ushort* __restrict__ B,
    void* __restrict__ Cp, int M, int N, int K) {
  __shared__ ushort a_lds[128 * 64];
  __shared__ ushort b_lds[128 * 64];
  const int tid = threadIdx.x;
  const int wid = tid >> 6, lane = tid & 63;
  const int l16 = lane & 15, lk = lane >> 4;
  const int wr = wid >> 1, wc = wid & 1;
  const size_t a_row0 = (size_t)blockIdx.y * 128;
  const size_t b_row0 = (size_t)blockIdx.x * 128;

  f32x4 acc[4][4] = {};

  for (int kt = 0; kt < K; kt += 64) {
    __syncthreads();  // prior-iteration LDS reads complete before overwrite
#pragma unroll
    for (int i = 0; i < 4; ++i) {
      int c = i * 256 + tid;               // 1024 16B-chunks per tile (8 per 128B row)
      int row = c >> 3, pos = c & 7;
      int src = pos ^ (row & 7);           // involution: pre-swizzled source
      gload_lds16(A + (a_row0 + row) * K + kt + src * 8, &a_lds[c * 8]);
      gload_lds16(B + (b_row0 + row) * K + kt + src * 8, &b_lds[c * 8]);
    }
    __syncthreads();  // drains vmcnt: LDS tiles ready

#pragma unroll
    for (int kk = 0; kk < 2; ++kk) {
      bf16x8 af[4], bf[4];
#pragma unroll
      for (int m = 0; m < 4; ++m) {
        int row = wr * 64 + m * 16 + l16;
        int ch = (kk * 4 + lk) ^ (row & 7);
        af[m] = *reinterpret_cast<const bf16x8*>(&a_lds[row * 64 + ch * 8]);
      }
#pragma unroll
      for (int n = 0; n < 4; ++n) {
        int row = wc * 64 + n * 16 + l16;
        int ch = (kk * 4 + lk) ^ (row & 7);
        bf[n] = *reinterpret_cast<const bf16x8*>(&b_lds[row * 64 + ch * 8]);
      }
#pragma unroll
      for (int m = 0; m < 4; ++m)
#pragma unroll
        for (int n = 0; n < 4; ++n)
          acc[m][n] = __builtin_amdgcn_mfma_f32_16x16x32_bf16(af[m], bf[n], acc[m][n], 0, 0, 0);
    }
  }

#pragma unroll
  for (int m = 0; m < 4; ++m) {
    int row_b = wr * 64 + m * 16 + lk * 4;
#pragma unroll
    for (int n = 0; n < 4; ++n) {
      int col = (int)b_row0 + wc * 64 + n * 16 + l16;
#pragma unroll
      for (int r = 0; r < 4; ++r) {
        size_t row = a_row0 + row_b + r;
        if constexpr (BF16_OUT)
          ((ushort*)Cp)[row * N + col] = f2bf(acc[m][n][r]);
        else
          ((float*)Cp)[row * N + col] = acc[m][n][r];
      }
    }
  }
}

// ---------------- O-proj GEMM, K-split x2 in one launch (4 blocks/CU), BK=64 ----------------
__global__ __launch_bounds__(256, 4) void gemm_o_ks(
    const ushort* __restrict__ A, const ushort* __restrict__ B,
    float* __restrict__ P0, float* __restrict__ P1) {
  __shared__ ushort a_lds[128 * 64];
  __shared__ ushort b_lds[128 * 64];
  const int bid = blockIdx.x;
  const int kh = bid >> 9;
  const int rem = bid & 511;
  const size_t b_row0 = (size_t)(rem & 31) * 128;   // N/128 = 32
  const size_t a_row0 = (size_t)(rem >> 5) * 128;   // M/128 = 16
  const int k0 = kh * 2048, k1 = k0 + 2048;
  float* __restrict__ P = kh ? P1 : P0;
  const int tid = threadIdx.x;
  const int wid = tid >> 6, lane = tid & 63;
  const int l16 = lane & 15, lk = lane >> 4;
  const int wr = wid >> 1, wc = wid & 1;

  f32x4 acc[4][4] = {};

  for (int kt = k0; kt < k1; kt += 64) {
    __syncthreads();
#pragma unroll
    for (int i = 0; i < 4; ++i) {
      int c = i * 256 + tid;
      int row = c >> 3, pos = c & 7;
      int src = pos ^ (row & 7);
      gload_lds16(A + (a_row0 + row) * HID + kt + src * 8, &a_lds[c * 8]);
      gload_lds16(B + (b_row0 + row) * HID + kt + src * 8, &b_lds[c * 8]);
    }
    __syncthreads();

#pragma unroll
    for (int kk = 0; kk < 2; ++kk) {
      bf16x8 af[4], bf[4];
#pragma unroll
      for (int m = 0; m < 4; ++m) {
        int row = wr * 64 + m * 16 + l16;
        int ch = (kk * 4 + lk) ^ (row & 7);
        af[m] = *reinterpret_cast<const bf16x8*>(&a_lds[row * 64 + ch * 8]);
      }
#pragma unroll
      for (int n = 0; n < 4; ++n) {
        int row = wc * 64 + n * 16 + l16;
        int ch = (kk * 4 + lk) ^ (row & 7);
        bf[n] = *reinterpret_cast<const bf16x8*>(&b_lds[row * 64 + ch * 8]);
      }
#pragma unroll
      for (int m = 0; m < 4; ++m)
#pragma unroll
        for (int n = 0; n < 4; ++n)
          acc[m][n] = __builtin_amdgcn_mfma_f32_16x16x32_bf16(af[m], bf[n], acc[m][n], 0, 0, 0);
    }
  }

#pragma unroll
  for (int m = 0; m < 4; ++m) {
    int row_b = wr * 64 + m * 16 + lk * 4;
#pragma unroll
    for (int n = 0; n < 4; ++n) {
      int col = (int)b_row0 + wc * 64 + n * 16 + l16;
#pragma unroll
      for (int r = 0; r < 4; ++r)
        P[(a_row0 + row_b + r) * HID + col] = acc[m][n][r];
    }
  }
}

__global__ void add_f32(const float* __restrict__ a, const float* __restrict__ b,
                        float* __restrict__ o, int n) {
  int i = (blockIdx.x * 256 + threadIdx.x) * 4;
  if (i >= n) return;
  float4 x = *reinterpret_cast<const float4*>(a + i);
  float4 y = *reinterpret_cast<const float4*>(b + i);
  float4 z; z.x = x.x + y.x; z.y = x.y + y.y; z.z = x.z + y.z; z.w = x.w + y.w;
  *reinterpret_cast<float4*>(o + i) = z;
}

// ---------------- fused RoPE (Q/K cols) + V transpose — independent QKV regions ----------------
__global__ void rope_and_tv(ushort* __restrict__ QKV, ushort* __restrict__ Vt) {
  if (blockIdx.x < 2560) {
    int idx = blockIdx.x * 256 + threadIdx.x;  // 2048 * 40 * 8 threads
    int dg = idx & 7;
    int t = idx >> 3;
    int s = t / 40;
    int hh = t - s * 40;
    if (s >= S_LEN) return;
    int col = (hh < NH) ? hh * HD : HID + (hh - NH) * HD;
    ushort* base = QKV + (size_t)s * QKV_N + col + dg * 8;

    union U { uint4 v; ushort u[8]; };
    U L, H, OL, OH;
    L.v = *reinterpret_cast<const uint4*>(base);
    H.v = *reinterpret_cast<const uint4*>(base + 64);
    const float C0 = 13.287712379549449f / 64.0f;  // log2(10000)/64
#pragma unroll
    for (int j = 0; j < 8; ++j) {
      int d = dg * 8 + j;
      float invf = exp2f(-(float)d * C0);
      float ang = (float)s * invf;
      float sn, cs;
      sincosf(ang, &sn, &cs);
      float xl = bf2f(L.u[j]), xh = bf2f(H.u[j]);
      OL.u[j] = f2bf(xl * cs - xh * sn);
      OH.u[j] = f2bf(xh * cs + xl * sn);
    }
    *reinterpret_cast<uint4*>(base) = OL.v;
    *reinterpret_cast<uint4*>(base + 64) = OH.v;
  } else {
    __shared__ ushort t[64][65];
    int local = blockIdx.x - 2560;             // 32 s-tiles x 2 d-tiles x 8 hkv
    int s0 = (local & 31) * 64;
    int d0 = ((local >> 5) & 1) * 64;
    int hkv = local >> 6;
    int tx = threadIdx.x & 63, ty = threadIdx.x >> 6;  // 64 x 4
#pragma unroll
    for (int i = 0; i < 64; i += 4)
      t[i + ty][tx] = QKV[(size_t)(s0 + i + ty) * QKV_N + HID + NKV * HD + hkv * HD + d0 + tx];
    __syncthreads();
#pragma unroll
    for (int i = 0; i < 64; i += 4)
      Vt[((size_t)hkv * HD + d0 + i + ty) * S_LEN + s0 + tx] = t[tx][i + ty];
  }
}

// ---------------- flash attention: swapped-QK^T 32x32 MFMA, in-register softmax ----------------
// R8-proven. Grid = 256 blocks; h=(lin&7)*4+((lin>>3)&3), p=lin>>5; panels {p,15-p}
// sequentially -> uniform 34 KV-tiles; XCD-local KV (1MB per hkv fits 4MB XCD L2).
__global__ __launch_bounds__(256, 2) void attn_kernel(
    const ushort* __restrict__ QKV, const ushort* __restrict__ Vt, ushort* __restrict__ AO) {
  constexpr float SCALE = 0.08838834764831845f;  // 1/sqrt(128)
  __shared__ ushort k_lds[2][64 * 128];   // [krow][128 d], 16B chunks XOR-swizzled by (row&7)
  __shared__ ushort v_lds[2][128 * 64];   // [d][64 s], 16B chunks XOR-swizzled by (row&7)

  const int lin = blockIdx.x;
  const int h = ((lin & 7) << 2) + ((lin >> 3) & 3);
  const int p = lin >> 5;                 // 0..7
  const int hkv = h >> 2;
  const int tid = threadIdx.x, wid = tid >> 6, lane = tid & 63;
  const int l32 = lane & 31;
  const int hi = lane >> 5;

  auto stageKV = [&](int buf, int kt) {
#pragma unroll
    for (int i = 0; i < 4; ++i) {
      int c = i * 256 + wid * 64 + lane;
      int row = c >> 4, ch = c & 15;
      int sch = ch ^ (row & 7);
      gload_lds16(QKV + (size_t)(kt * 64 + row) * QKV_N + HID + hkv * HD + sch * 8,
                  &k_lds[buf][c * 8]);
    }
#pragma unroll
    for (int i = 0; i < 4; ++i) {
      int c = i * 256 + wid * 64 + lane;
      int row = c >> 3, ch = c & 7;
      int sch = ch ^ (row & 7);
      gload_lds16(Vt + ((size_t)hkv * HD + row) * S_LEN + (size_t)kt * 64 + sch * 8,
                  &v_lds[buf][c * 8]);
    }
  };

  for (int pi = 0; pi < 2; ++pi) {
    const int qb = pi ? (15 - p) : p;
    const int q0 = qb * 128;
    const int qg = q0 + wid * 32 + l32;   // this lane's q row

    bf16x8 qf[8];
    {
      const ushort* qrow = QKV + (size_t)qg * QKV_N + h * HD + hi * 8;
#pragma unroll
      for (int ds = 0; ds < 8; ++ds)
        qf[ds] = *reinterpret_cast<const bf16x8*>(qrow + ds * 16);
    }

    float m_run = -1e30f, l_run = 0.f;
    f32x16 oacc[4] = {};   // oacc[f][r] = O[q=l32][d = f*32 + crow(r,hi)]

    stageKV(0, 0);
    __syncthreads();

    const int nt = 2 * qb + 2;
    for (int kt = 0; kt < nt; ++kt) {
      const int cur = kt & 1;
      if (kt + 1 < nt) stageKV(cur ^ 1, kt + 1);

      if (kt * 64 <= q0 + wid * 32 + 31) {
        float pv[32];
        __builtin_amdgcn_s_setprio(1);
#pragma unroll
        for (int kf = 0; kf < 2; ++kf) {
          f32x16 s = {};
          int rk = kf * 32 + l32;
#pragma unroll
          for (int ds = 0; ds < 8; ++ds) {
            int c16 = (ds * 2 + hi) ^ (rk & 7);
            bf16x8 kfr = *reinterpret_cast<const bf16x8*>(&k_lds[cur][rk * 128 + c16 * 8]);
            s = __builtin_amdgcn_mfma_f32_32x32x16_bf16(kfr, qf[ds], s, 0, 0, 0);
          }
#pragma unroll
          for (int r = 0; r < 16; ++r) pv[kf * 16 + r] = s[r] * SCALE;
        }
        __builtin_amdgcn_s_setprio(0);

        if (kt * 64 + 63 > q0 + wid * 32) {  // diagonal tile: causal mask
#pragma unroll
          for (int kf = 0; kf < 2; ++kf)
#pragma unroll
            for (int r = 0; r < 16; ++r) {
              int kl = kf * 32 + (r & 3) + 8 * (r >> 2) + 4 * hi;
              if (kt * 64 + kl > qg) pv[kf * 16 + r] = -1e30f;
            }
        }

        float mt = pv[0];
#pragma unroll
        for (int i = 1; i < 32; ++i) mt = fmaxf(mt, pv[i]);
        mt = fmaxf(mt, __shfl_xor(mt, 32, 64));
        float mn = fmaxf(m_run, mt);
        float alpha = __expf(m_run - mn);
        float ls = 0.f;
#pragma unroll
        for (int i = 0; i < 32; ++i) { pv[i] = __expf(pv[i] - mn); ls += pv[i]; }
        ls += __shfl_xor(ls, 32, 64);
        l_run = l_run * alpha + ls;
        m_run = mn;
#pragma unroll
        for (int f = 0; f < 4; ++f)
#pragma unroll
          for (int r = 0; r < 16; ++r) oacc[f][r] *= alpha;

        // pack P -> PV B-operand (T12: cvt_pk + permlane32_swap)
        union PW { uint32_t w[4]; bf16x8 v; } pa[4];
#pragma unroll
        for (int ks = 0; ks < 4; ++ks) {
          uint32_t x0, x1, y0, y1;
          asm("v_cvt_pk_bf16_f32 %0, %1, %2" : "=v"(x0) : "v"(pv[8 * ks + 0]), "v"(pv[8 * ks + 1]));
          asm("v_cvt_pk_bf16_f32 %0, %1, %2" : "=v"(x1) : "v"(pv[8 * ks + 2]), "v"(pv[8 * ks + 3]));
          asm("v_cvt_pk_bf16_f32 %0, %1, %2" : "=v"(y0) : "v"(pv[8 * ks + 4]), "v"(pv[8 * ks + 5]));
          asm("v_cvt_pk_bf16_f32 %0, %1, %2" : "=v"(y1) : "v"(pv[8 * ks + 6]), "v"(pv[8 * ks + 7]));
          u32x2 r0 = __builtin_amdgcn_permlane32_swap(x0, y0, false, false);
          u32x2 r1 = __builtin_amdgcn_permlane32_swap(x1, y1, false, false);
          pa[ks].w[0] = r0.x; pa[ks].w[1] = r1.x; pa[ks].w[2] = r0.y; pa[ks].w[3] = r1.y;
        }

        __builtin_amdgcn_s_setprio(1);
#pragma unroll
        for (int ks = 0; ks < 4; ++ks) {
#pragma unroll
          for (int f = 0; f < 4; ++f) {
            int dv = f * 32 + l32;
            int c8 = (2 * ks + hi) ^ (dv & 7);
            bf16x8 vfr = *reinterpret_cast<const bf16x8*>(&v_lds[cur][dv * 64 + c8 * 8]);
            oacc[f] = __builtin_amdgcn_mfma_f32_32x32x16_bf16(vfr, pa[ks].v, oacc[f], 0, 0, 0);
          }
        }
        __builtin_amdgcn_s_setprio(0);
      }

      __syncthreads();
    }

    float inv_l = 1.0f / l_run;
    ushort* aorow = AO + (size_t)qg * HID + h * HD;
#pragma unroll
    for (int f = 0; f < 4; ++f)
#pragma unroll
      for (int g = 0; g < 4; ++g) {
        ushort4 o;
        o.x = f2bf(oacc[f][g * 4 + 0] * inv_l);
        o.y = f2bf(oacc[f][g * 4 + 1] * inv_l);
        o.z = f2bf(oacc[f][g * 4 + 2] * inv_l);
        o.w = f2bf(oacc[f][g * 4 + 3] * inv_l);
        *reinterpret_cast<ushort4*>(aorow + f * 32 + g * 8 + 4 * hi) = o;
      }
  }
}

// ---------------- launcher ----------------
extern "C" void kernel_launch(void* const* d_in, const int* in_sizes, int n_in,
                              void* d_out, int out_size, void* d_ws, size_t ws_size,
                              hipStream_t stream) {
  (void)in_sizes; (void)n_in; (void)out_size;
  const float* hs = (const float*)d_in[0];
  const float* Wq = (const float*)d_in[1];
  const float* Wk = (const float*)d_in[2];
  const float* Wv = (const float*)d_in[3];
  const float* Wo = (const float*)d_in[4];
  float* out = (float*)d_out;

  // workspace layout (bytes)
  char* ws = (char*)d_ws;
  const size_t OFF_HSB   = 0;                         // 2048*4096 bf16 = 16 MB
  const size_t OFF_WQKVT = OFF_HSB + 16777216;        // 6144*4096 bf16 = 48 MB
  const size_t OFF_WOT   = OFF_WQKVT + 50331648;      // 4096*4096 bf16 = 32 MB
  const size_t OFF_QKV   = OFF_WOT + 33554432;        // 2048*6144 bf16 = 24 MB
  const size_t OFF_VT    = OFF_QKV + 25165824;        // 8*128*2048 bf16 = 4 MB
  const size_t OFF_AO    = OFF_VT + 4194304;          // 2048*4096 bf16 = 16 MB
  if (ws_size < OFF_AO + 16777216) return;            // ~140 MB needed

  ushort* hsb   = (ushort*)(ws + OFF_HSB);
  ushort* WqkvT = (ushort*)(ws + OFF_WQKVT);
  ushort* WoT   = (ushort*)(ws + OFF_WOT);
  ushort* QKV   = (ushort*)(ws + OFF_QKV);
  ushort* Vt    = (ushort*)(ws + OFF_VT);
  ushort* AO    = (ushort*)(ws + OFF_AO);
  // f32 partials for the K-split O-proj, overlaid on hsb+WqkvT (both dead after QKV GEMM)
  float* P0 = (float*)(ws + 0);                       // 32 MB
  float* P1 = (float*)(ws + 33554432);                // 32 MB

  prep_all<<<49152, 256, 0, stream>>>(hs, Wq, Wk, Wv, Wo, hsb, WqkvT, WoT);
  gemm_bt<true><<<dim3(QKV_N / 128, S_LEN / 128), 256, 0, stream>>>(hsb, WqkvT, QKV, S_LEN, QKV_N, HID);
  rope_and_tv<<<3072, 256, 0, stream>>>(QKV, Vt);
  attn_kernel<<<256, 256, 0, stream>>>(QKV, Vt, AO);
  gemm_o_ks<<<1024, 256, 0, stream>>>(AO, WoT, P0, P1);
  add_f32<<<8192, 256, 0, stream>>>(P0, P1, out, S_LEN * HID);
}